// Round 10
// baseline (328.588 us; speedup 1.0000x reference)
//
#include <hip/hip_runtime.h>
#include <hip/hip_bf16.h>
#include <cstdint>
#include <cstddef>

#define BB 2
#define SS 2048
#define HH 2048
#define NHH 16
#define DHH 128

using f32x4  = __attribute__((ext_vector_type(4))) float;
using bf16x8 = __attribute__((ext_vector_type(8))) __bf16;
using bf16x4 = __attribute__((ext_vector_type(4))) __bf16;
using bfloat = __bf16;

__device__ inline void gload_lds16(const void* g, void* l) {
    __builtin_amdgcn_global_load_lds(
        (const __attribute__((address_space(1))) void*)g,
        (__attribute__((address_space(3))) void*)l, 16, 0, 0);
}

__device__ inline f32x4 mfma16(bf16x8 a, bf16x8 b, f32x4 c) {
    return __builtin_amdgcn_mfma_f32_16x16x32_bf16(a, b, c, 0, 0, 0);
}

template <int CTRL>
__device__ inline float dpp_max_step(float x) {
    int y = __builtin_amdgcn_update_dpp(0, __builtin_bit_cast(int, x), CTRL, 0xf, 0xf, false);
    return fmaxf(x, __builtin_bit_cast(float, y));
}
__device__ inline float rowmax16(float x) {
    x = dpp_max_step<0x121>(x);
    x = dpp_max_step<0x122>(x);
    x = dpp_max_step<0x124>(x);
    x = dpp_max_step<0x128>(x);
    return x;
}

// ---------------- fp32 -> bf16 conversion ----------------
__global__ void cvt_bf16(const float* __restrict__ in, bfloat* __restrict__ out, int n4) {
    int i = blockIdx.x * blockDim.x + threadIdx.x;
    if (i >= n4) return;
    float4 v = reinterpret_cast<const float4*>(in)[i];
    bf16x4 o;
    o[0] = (bfloat)v.x; o[1] = (bfloat)v.y; o[2] = (bfloat)v.z; o[3] = (bfloat)v.w;
    reinterpret_cast<bf16x4*>(out)[i] = o;
}

__global__ void cvt_bf16_w(const float* __restrict__ s0, const float* __restrict__ s1,
                           const float* __restrict__ s2, const float* __restrict__ s3,
                           bfloat* __restrict__ d0, bfloat* __restrict__ d1,
                           bfloat* __restrict__ d2, bfloat* __restrict__ d3) {
    int sel = blockIdx.x >> 12;
    int i = (blockIdx.x & 4095) * 256 + threadIdx.x;
    const float* s = sel == 0 ? s0 : sel == 1 ? s1 : sel == 2 ? s2 : s3;
    bfloat* d = sel == 0 ? d0 : sel == 1 ? d1 : sel == 2 ? d2 : d3;
    float4 v = reinterpret_cast<const float4*>(s)[i];
    bf16x4 o;
    o[0] = (bfloat)v.x; o[1] = (bfloat)v.y; o[2] = (bfloat)v.z; o[3] = (bfloat)v.w;
    reinterpret_cast<bf16x4*>(d)[i] = o;
}

// ---------------- RoPE tables (S x 64) ----------------
__global__ void rope_table(float* __restrict__ cosT, float* __restrict__ sinT) {
    int i = blockIdx.x * blockDim.x + threadIdx.x;
    if (i >= SS * 64) return;
    int s = i >> 6, j = i & 63;
    float invf = powf(10000.0f, -(float)j / 64.0f);
    float ang = (float)s * invf;
    cosT[i] = cosf(ang);
    sinT[i] = sinf(ang);
}

// ======== 256x128 tile K-loop, BK=32, 4 waves (2Mx2N, per-wave 128x64) ========
// R8's proven 2-phase double-buffered loop; 2 blocks/CU desync provides the
// MFMA<->LDS overlap (m114).  Per-wave 128x64 gives 12 b128-reads / 32 MFMA =
// 0.375 (LDS-bound threshold is 0.4).  Counted vmcnt(6): tile kt+1's 6 loads
// in flight across the compute phase; never drained mid-loop.
// LDS swizzle for 64B rows: unit u' = u ^ ((r>>1)&3)  -> frag ds_read_b128
// lands on 8 distinct (row-parity, unit) bank groups over 16 lanes = 2-way
// aliasing = free (m136).  Applied both-sides: pre-swizzled global source +
// swizzled read offsets (rule #21).
__device__ __forceinline__ void kloop(const bfloat* __restrict__ Ag,
                                      const bfloat* __restrict__ Bg,
                                      f32x4 (&acc)[8][4]) {
    constexpr int K = HH, NT = K / 32;
    __shared__ bfloat As[2][256 * 32];
    __shared__ bfloat Bs[2][128 * 32];
    const int t = threadIdx.x, l = t & 63, lr = l & 15, lg = l >> 4;
    const int w = t >> 6, wr = w >> 1, wc = w & 1;
    const int ubase = t & ~63;   // wave-uniform 16B-unit base

    auto stage = [&](int buf, int kt) {
#pragma unroll
        for (int i = 0; i < 4; i++) {
            int idx = i * 256 + t;               // 0..1023 A units
            int r = idx >> 2, u = idx & 3;
            int us = u ^ ((r >> 1) & 3);
            gload_lds16(Ag + (size_t)r * K + kt * 32 + us * 8,
                        &As[buf][(i * 256 + ubase) * 8]);
        }
#pragma unroll
        for (int i = 0; i < 2; i++) {
            int idx = i * 256 + t;               // 0..511 B units
            int r = idx >> 2, u = idx & 3;
            int us = u ^ ((r >> 1) & 3);
            gload_lds16(Bg + (size_t)r * K + kt * 32 + us * 8,
                        &Bs[buf][(i * 256 + ubase) * 8]);
        }
    };

    int brow[4];
#pragma unroll
    for (int nf = 0; nf < 4; nf++)
        brow[nf] = wc * 32 + (nf & 1) * 16 + (nf >> 1) * 64 + lr;

    stage(0, 0);

#pragma unroll 1
    for (int kt = 0; kt < NT; ++kt) {
        const int buf = kt & 1;
        if (kt + 1 < NT) {
            stage(buf ^ 1, kt + 1);                            // 6 loads in flight
            asm volatile("s_waitcnt vmcnt(6)" ::: "memory");   // tile kt resident
        } else {
            asm volatile("s_waitcnt vmcnt(0)" ::: "memory");
        }
        __builtin_amdgcn_s_barrier();
        __builtin_amdgcn_sched_barrier(0);

        const bfloat* A_ = As[buf];
        const bfloat* B_ = Bs[buf];
        bf16x8 bfr[4];
#pragma unroll
        for (int nf = 0; nf < 4; nf++) {
            int r = brow[nf];
            bfr[nf] = *reinterpret_cast<const bf16x8*>(
                &B_[(r * 4 + (lg ^ ((r >> 1) & 3))) * 8]);
        }
        bf16x8 af[8];
#pragma unroll
        for (int mf = 0; mf < 8; mf++) {
            int r = wr * 128 + mf * 16 + lr;
            af[mf] = *reinterpret_cast<const bf16x8*>(
                &A_[(r * 4 + (lg ^ ((r >> 1) & 3))) * 8]);
        }
        __builtin_amdgcn_s_setprio(1);
#pragma unroll
        for (int mf = 0; mf < 8; mf++)
#pragma unroll
            for (int nf = 0; nf < 4; nf++)
                acc[mf][nf] = mfma16(af[mf], bfr[nf], acc[mf][nf]);
        __builtin_amdgcn_s_setprio(0);
        __builtin_amdgcn_sched_barrier(0);
        __builtin_amdgcn_s_barrier();        // buf reads done before next restage
    }
}

// ================= fused QKV GEMM (256x128 tiles, 256 threads) =================
// grid (16, 48): blockIdx.y>>4 selects {Q, K, V}; n0 = (y&15)*128 = one head.
__global__ __launch_bounds__(256, 2)
void gemm_qkv(const bfloat* __restrict__ A,
              const bfloat* __restrict__ Bq, const bfloat* __restrict__ Bk,
              const bfloat* __restrict__ Bv,
              const float* __restrict__ bq, const float* __restrict__ bk,
              const float* __restrict__ bv,
              bfloat* __restrict__ Qo, bfloat* __restrict__ Ko, bfloat* __restrict__ Vto,
              const float* __restrict__ cosT, const float* __restrict__ sinT) {
    constexpr int K = HH, N = HH;
    const int sel = blockIdx.y >> 4;
    const bfloat* Bt = sel == 0 ? Bq : sel == 1 ? Bk : Bv;
    const float* bias = sel == 0 ? bq : sel == 1 ? bk : bv;
    const int m0 = blockIdx.x * 256, n0 = (blockIdx.y & 15) * 128;

    f32x4 acc[8][4] = {};
    kloop(A + (size_t)m0 * K, Bt + (size_t)n0 * K, acc);

    const int t = threadIdx.x, l = t & 63, lr = l & 15, lg = l >> 4;
    const int w = t >> 6, wr = w >> 1, wc = w & 1;

    if (sel == 2) {   // V: write transposed (b, h, d, s)
#pragma unroll
        for (int mf = 0; mf < 8; mf++) {
            int row = m0 + wr * 128 + mf * 16 + lg * 4;
#pragma unroll
            for (int nf = 0; nf < 4; nf++) {
                int col = n0 + wc * 32 + (nf & 1) * 16 + (nf >> 1) * 64 + lr;
                float bv_ = bias[col];
#pragma unroll
                for (int j = 0; j < 4; j++) {
                    int r = row + j;
                    Vto[((size_t)((r >> 11) * HH + col)) * SS + (r & (SS - 1))] =
                        (bfloat)(acc[mf][nf][j] + bv_);
                }
            }
        }
    } else {          // Q/K: RoPE epilogue (Q also pre-scaled by 1/sqrt(DH))
        bfloat* C = sel == 0 ? Qo : Ko;
        const float qs = sel == 0 ? 0.088388347648318447f : 1.0f;
#pragma unroll
        for (int mf = 0; mf < 8; mf++) {
            int row = m0 + wr * 128 + mf * 16 + lg * 4;
#pragma unroll
            for (int nf = 0; nf < 2; nf++) {
                int d = wc * 32 + nf * 16 + lr;      // 0..63 within head
                int col1 = n0 + d, col2 = col1 + 64;
                float b1 = bias[col1], b2 = bias[col2];
#pragma unroll
                for (int j = 0; j < 4; j++) {
                    int r = row + j, s = r & (SS - 1);
                    float c  = cosT[s * 64 + d];
                    float sn = sinT[s * 64 + d];
                    float x1 = acc[mf][nf][j] + b1;
                    float x2 = acc[mf][nf + 2][j] + b2;
                    C[(size_t)r * N + col1] = (bfloat)((x1 * c - x2 * sn) * qs);
                    C[(size_t)r * N + col2] = (bfloat)((x2 * c + x1 * sn) * qs);
                }
            }
        }
    }
}

// ---------------- out-proj GEMM (256x128 tiles, f32 out) ----------------
// grid (16, 16) = 256 blocks at 2/CU -> no dispatch tail.
__global__ __launch_bounds__(256, 2)
void gemm_out(const bfloat* __restrict__ A, const bfloat* __restrict__ Bt,
              const float* __restrict__ bias, float* __restrict__ C) {
    constexpr int K = HH, N = HH;
    const int m0 = blockIdx.x * 256, n0 = blockIdx.y * 128;

    f32x4 acc[8][4] = {};
    kloop(A + (size_t)m0 * K, Bt + (size_t)n0 * K, acc);

    const int t = threadIdx.x, l = t & 63, lr = l & 15, lg = l >> 4;
    const int w = t >> 6, wr = w >> 1, wc = w & 1;
#pragma unroll
    for (int mf = 0; mf < 8; mf++) {
        int row = m0 + wr * 128 + mf * 16 + lg * 4;
#pragma unroll
        for (int nf = 0; nf < 4; nf++) {
            int col = n0 + wc * 32 + (nf & 1) * 16 + (nf >> 1) * 64 + lr;
            float bv = bias[col];
#pragma unroll
            for (int j = 0; j < 4; j++)
                C[(size_t)(row + j) * N + col] = acc[mf][nf][j] + bv;
        }
    }
}

// ---------------- Flash attention (causal), KVB=64, single-buffered LDS ----
__global__ __launch_bounds__(256, 4)
void attn_fwd(const bfloat* __restrict__ Q, const bfloat* __restrict__ K,
              const bfloat* __restrict__ Vt, bfloat* __restrict__ O) {
    __shared__ bfloat Ks[64 * 128];
    __shared__ bfloat Vs[128 * 64];
    __shared__ bfloat Pw[4][16 * 64];

    const int t = threadIdx.x, w = t >> 6, l = t & 63;
    const int lr = l & 15, lg = l >> 4;
    const int swz = (lr & 7) << 4;

    const int f = blockIdx.x;
    const int xcd = f & 7, slot = f >> 3;
    const int bh = xcd + 8 * (slot >> 5);
    const int qidx = 31 - (slot & 31);
    const int b = bh >> 4, h = bh & 15;
    const int q0 = qidx * 64 + w * 16;

    const size_t bo_ = (size_t)b * SS * HH + (size_t)h * DHH;
    const bfloat* Qp = Q + bo_;
    const bfloat* Kp = K + bo_;
    const bfloat* Vp = Vt + (size_t)(b * NHH + h) * DHH * SS;
    bfloat* Op = O + bo_;

    auto stage = [&](int kv0) {
#pragma unroll
        for (int i = 0; i < 4; i++) {
            int Ub = (i * 4 + w) * 64;
            int U = Ub + l;
            int r = U >> 4;
            int u = (U & 15) ^ (r & 7);
            gload_lds16(Kp + (size_t)(kv0 + r) * HH + u * 8, &Ks[Ub * 8]);
        }
#pragma unroll
        for (int i = 0; i < 4; i++) {
            int Ub = (i * 4 + w) * 64;
            int U = Ub + l;
            int r = U >> 3;
            int u = (U & 7) ^ (r & 7);
            gload_lds16(Vp + (size_t)r * SS + kv0 + u * 8, &Vs[Ub * 8]);
        }
    };

    bf16x8 qf[4];
#pragma unroll
    for (int kt = 0; kt < 4; kt++)
        qf[kt] = *reinterpret_cast<const bf16x8*>(Qp + (size_t)(q0 + lr) * HH + kt * 32 + lg * 8);

    bf16x8 ones;
#pragma unroll
    for (int e = 0; e < 8; e++) ones[e] = (bfloat)1.0f;

    f32x4 o[8] = {};
    f32x4 lsv = {};
    float m[4];
#pragma unroll
    for (int j = 0; j < 4; j++) m[j] = -1e30f;

    const int nkv = qidx + 1;

    for (int kv = 0; kv < nkv; ++kv) {
        stage(kv * 64);
        __syncthreads();

        const char* KB = (const char*)&Ks[0];
        const char* VB = (const char*)&Vs[0];

        f32x4 sc[4] = {};
        __builtin_amdgcn_s_setprio(1);
#pragma unroll
        for (int kt = 0; kt < 4; kt++) {
            const int col = (kt * 64 + lg * 16);
#pragma unroll
            for (int kb = 0; kb < 4; kb++) {
                bf16x8 kf = *reinterpret_cast<const bf16x8*>(
                    KB + (kb * 16 + lr) * 256 + (col ^ swz));
                sc[kb] = mfma16(qf[kt], kf, sc[kb]);
            }
        }
        __builtin_amdgcn_s_setprio(0);

        const bool diag = (kv == nkv - 1);
        float p[4][4], alpha[4];
        bool ga = false;
#pragma unroll
        for (int j = 0; j < 4; j++) {
            float v0 = sc[0][j], v1 = sc[1][j], v2 = sc[2][j], v3 = sc[3][j];
            if (diag) {
                int qr = q0 + lg * 4 + j;
                int k0 = kv * 64 + lr;
                if (k0      > qr) v0 = -1e30f;
                if (k0 + 16 > qr) v1 = -1e30f;
                if (k0 + 32 > qr) v2 = -1e30f;
                if (k0 + 48 > qr) v3 = -1e30f;
            }
            float mx = rowmax16(fmaxf(fmaxf(v0, v1), fmaxf(v2, v3)));
            bool grow = mx > m[j] + 8.0f;
            float mn = grow ? mx : m[j];
            alpha[j] = grow ? __expf(m[j] - mn) : 1.0f;
            m[j] = mn;
            ga = ga || grow;
            p[0][j] = __expf(v0 - mn);
            p[1][j] = __expf(v1 - mn);
            p[2][j] = __expf(v2 - mn);
            p[3][j] = __expf(v3 - mn);
        }
        if (__any(ga)) {
#pragma unroll
            for (int j = 0; j < 4; j++) {
                lsv[j] *= alpha[j];
#pragma unroll
                for (int nt = 0; nt < 8; nt++) o[nt][j] *= alpha[j];
            }
        }

        char* pwb = (char*)&Pw[w][0];
#pragma unroll
        for (int j = 0; j < 4; j++) {
            int q = lg * 4 + j;
            int qs = (q & 7) << 4;
#pragma unroll
            for (int kb = 0; kb < 4; kb++)
                *(bfloat*)(pwb + q * 128 + ((kb * 32 + lr * 2) ^ qs)) = (bfloat)p[kb][j];
        }
        asm volatile("s_waitcnt lgkmcnt(0)" ::: "memory");
        __builtin_amdgcn_sched_barrier(0);

        const char* pwr = (const char*)&Pw[w][0];
        bf16x8 pa0 = *reinterpret_cast<const bf16x8*>(pwr + lr * 128 + ((lg * 16) ^ swz));
        bf16x8 pa1 = *reinterpret_cast<const bf16x8*>(pwr + lr * 128 + ((64 + lg * 16) ^ swz));
        __builtin_amdgcn_s_setprio(1);
        lsv = mfma16(pa0, ones, lsv);
        lsv = mfma16(pa1, ones, lsv);
#pragma unroll
        for (int nt = 0; nt < 8; nt++) {
            const char* vb = VB + (nt * 16 + lr) * 128;
            bf16x8 vf0 = *reinterpret_cast<const bf16x8*>(vb + ((lg * 16) ^ swz));
            bf16x8 vf1 = *reinterpret_cast<const bf16x8*>(vb + ((64 + lg * 16) ^ swz));
            o[nt] = mfma16(pa0, vf0, o[nt]);
            o[nt] = mfma16(pa1, vf1, o[nt]);
        }
        __builtin_amdgcn_s_setprio(0);
        __syncthreads();
    }

#pragma unroll
    for (int j = 0; j < 4; j++) {
        float inv = 1.0f / lsv[j];
        int row = q0 + lg * 4 + j;
#pragma unroll
        for (int nt = 0; nt < 8; nt++)
            Op[(size_t)row * HH + nt * 16 + lr] = (bfloat)(o[nt][j] * inv);
    }
}

// ---------------- launch ----------------
extern "C" void kernel_launch(void* const* d_in, const int* in_sizes, int n_in,
                              void* d_out, int out_size, void* d_ws, size_t ws_size,
                              hipStream_t stream) {
    (void)in_sizes; (void)n_in; (void)out_size; (void)ws_size;
    const float* hs = (const float*)d_in[0];
    const float* Wq = (const float*)d_in[2];
    const float* bq = (const float*)d_in[3];
    const float* Wk = (const float*)d_in[4];
    const float* bk = (const float*)d_in[5];
    const float* Wv = (const float*)d_in[6];
    const float* bv = (const float*)d_in[7];
    const float* Wo = (const float*)d_in[8];
    const float* bo = (const float*)d_in[9];

    char* ws = (char*)d_ws;
    size_t off = 0;
    auto alloc = [&](size_t bytes) { void* p = ws + off; off += (bytes + 255) & ~(size_t)255; return p; };
    const size_t MK = (size_t)BB * SS * HH;   // 8M elems
    const size_t NK = (size_t)HH * HH;        // 4M elems

    bfloat* Xb  = (bfloat*)alloc(MK * 2);
    bfloat* Wqb = (bfloat*)alloc(NK * 2);
    bfloat* Wkb = (bfloat*)alloc(NK * 2);
    bfloat* Wvb = (bfloat*)alloc(NK * 2);
    bfloat* Wob = (bfloat*)alloc(NK * 2);
    bfloat* Qb  = (bfloat*)alloc(MK * 2);
    bfloat* Kb  = (bfloat*)alloc(MK * 2);
    bfloat* Vtb = (bfloat*)alloc(MK * 2);     // (b, h, d, s)
    float*  cosT = (float*)alloc((size_t)SS * 64 * 4);
    float*  sinT = (float*)alloc((size_t)SS * 64 * 4);
    bfloat* AOb = Xb;   // reuse: X no longer needed after QKV GEMM

    cvt_bf16<<<(int)(MK / 4 / 256), 256, 0, stream>>>(hs, Xb, (int)(MK / 4));
    cvt_bf16_w<<<4 * 4096, 256, 0, stream>>>(Wq, Wk, Wv, Wo, Wqb, Wkb, Wvb, Wob);
    rope_table<<<(SS * 64 + 255) / 256, 256, 0, stream>>>(cosT, sinT);

    gemm_qkv<<<dim3(BB * SS / 256, 48), 256, 0, stream>>>(
        Xb, Wqb, Wkb, Wvb, bq, bk, bv, Qb, Kb, Vtb, cosT, sinT);

    attn_fwd<<<1024, 256, 0, stream>>>(Qb, Kb, Vtb, AOb);

    gemm_out<<<dim3(BB * SS / 256, HH / 128), 256, 0, stream>>>(
        AOb, Wob, bo, (float*)d_out);
}

// Round 11
// 313.071 us; speedup vs baseline: 1.0496x; 1.0496x over previous
//
#include <hip/hip_runtime.h>
#include <hip/hip_bf16.h>
#include <cstdint>
#include <cstddef>

#define BB 2
#define SS 2048
#define HH 2048
#define NHH 16
#define DHH 128

using f32x4  = __attribute__((ext_vector_type(4))) float;
using bf16x8 = __attribute__((ext_vector_type(8))) __bf16;
using bf16x4 = __attribute__((ext_vector_type(4))) __bf16;
using bfloat = __bf16;

__device__ inline void gload_lds16(const void* g, void* l) {
    __builtin_amdgcn_global_load_lds(
        (const __attribute__((address_space(1))) void*)g,
        (__attribute__((address_space(3))) void*)l, 16, 0, 0);
}

__device__ inline f32x4 mfma16(bf16x8 a, bf16x8 b, f32x4 c) {
    return __builtin_amdgcn_mfma_f32_16x16x32_bf16(a, b, c, 0, 0, 0);
}

template <int CTRL>
__device__ inline float dpp_max_step(float x) {
    int y = __builtin_amdgcn_update_dpp(0, __builtin_bit_cast(int, x), CTRL, 0xf, 0xf, false);
    return fmaxf(x, __builtin_bit_cast(float, y));
}
__device__ inline float rowmax16(float x) {
    x = dpp_max_step<0x121>(x);
    x = dpp_max_step<0x122>(x);
    x = dpp_max_step<0x124>(x);
    x = dpp_max_step<0x128>(x);
    return x;
}

// -------- merged prep: X cvt (8192 blk) + 4 weight cvts (16384 blk) + rope (512 blk)
__global__ void prep_all(const float* __restrict__ hs,
                         const float* __restrict__ w0, const float* __restrict__ w1,
                         const float* __restrict__ w2, const float* __restrict__ w3,
                         bfloat* __restrict__ xb,
                         bfloat* __restrict__ d0, bfloat* __restrict__ d1,
                         bfloat* __restrict__ d2, bfloat* __restrict__ d3,
                         float* __restrict__ cosT, float* __restrict__ sinT) {
    const int bid = blockIdx.x, tid = threadIdx.x;
    if (bid < 8192 + 16384) {
        const float* s;
        bfloat* d;
        int i;
        if (bid < 8192) {
            s = hs; d = xb; i = bid * 256 + tid;
        } else {
            int b2 = bid - 8192, sel = b2 >> 12;
            s = sel == 0 ? w0 : sel == 1 ? w1 : sel == 2 ? w2 : w3;
            d = sel == 0 ? d0 : sel == 1 ? d1 : sel == 2 ? d2 : d3;
            i = (b2 & 4095) * 256 + tid;
        }
        float4 v = reinterpret_cast<const float4*>(s)[i];
        bf16x4 o;
        o[0] = (bfloat)v.x; o[1] = (bfloat)v.y; o[2] = (bfloat)v.z; o[3] = (bfloat)v.w;
        reinterpret_cast<bf16x4*>(d)[i] = o;
    } else {
        int i = (bid - 24576) * 256 + tid;      // 0 .. SS*64-1
        int s = i >> 6, j = i & 63;
        float invf = powf(10000.0f, -(float)j / 64.0f);
        float ang = (float)s * invf;
        cosT[i] = cosf(ang);
        sinT[i] = sinf(ang);
    }
}

// ======== 128x128 tile K-loop, BK=32, 4 waves, 2-phase double-buffered ========
// (R8 verbatim -- best measured GEMM core: 143.8-148.8 us for QKV.)
// Counted vmcnt(4); raw s_barrier; swizzle u' = u ^ (r&3) ^ ((r>>2)&1) both-sides.
__device__ __forceinline__ void kloop128(const bfloat* __restrict__ Ag,
                                         const bfloat* __restrict__ Bg,
                                         f32x4 (&acc)[4][4]) {
    constexpr int K = HH, NT = K / 32;
    __shared__ bfloat As[2][128 * 32];
    __shared__ bfloat Bs[2][128 * 32];
    const int t = threadIdx.x, l = t & 63, lr = l & 15, lg = l >> 4;
    const int w = t >> 6, wm = (w >> 1) * 64, wc = w & 1;
    const int ubase = t & ~63;

    auto stage = [&](int buf, int kt) {
#pragma unroll
        for (int i = 0; i < 2; i++) {
            int idx = i * 256 + t;
            int r = idx >> 2, u = idx & 3;
            int us = u ^ (r & 3) ^ ((r >> 2) & 1);
            gload_lds16(Ag + (size_t)r * K + kt * 32 + us * 8,
                        &As[buf][(i * 256 + ubase) * 8]);
        }
#pragma unroll
        for (int i = 0; i < 2; i++) {
            int idx = i * 256 + t;
            int r = idx >> 2, u = idx & 3;
            int us = u ^ (r & 3) ^ ((r >> 2) & 1);
            gload_lds16(Bg + (size_t)r * K + kt * 32 + us * 8,
                        &Bs[buf][(i * 256 + ubase) * 8]);
        }
    };

    stage(0, 0);

#pragma unroll 1
    for (int kt = 0; kt < NT; ++kt) {
        const int buf = kt & 1;
        if (kt + 1 < NT) {
            stage(buf ^ 1, kt + 1);
            asm volatile("s_waitcnt vmcnt(4)" ::: "memory");
        } else {
            asm volatile("s_waitcnt vmcnt(0)" ::: "memory");
        }
        __builtin_amdgcn_s_barrier();
        __builtin_amdgcn_sched_barrier(0);

        const bfloat* A_ = As[buf];
        const bfloat* B_ = Bs[buf];
        bf16x8 af[4], bfr[4];
#pragma unroll
        for (int mi = 0; mi < 4; mi++) {
            int row = wm + mi * 16 + lr;
            int us = lg ^ (row & 3) ^ ((row >> 2) & 1);
            af[mi] = *reinterpret_cast<const bf16x8*>(&A_[row * 32 + us * 8]);
        }
#pragma unroll
        for (int ni = 0; ni < 4; ni++) {
            int row = wc * 32 + (ni & 1) * 16 + (ni >> 1) * 64 + lr;
            int us = lg ^ (row & 3) ^ ((row >> 2) & 1);
            bfr[ni] = *reinterpret_cast<const bf16x8*>(&B_[row * 32 + us * 8]);
        }
        __builtin_amdgcn_s_setprio(1);
#pragma unroll
        for (int mi = 0; mi < 4; mi++)
#pragma unroll
            for (int ni = 0; ni < 4; ni++)
                acc[mi][ni] = mfma16(af[mi], bfr[ni], acc[mi][ni]);
        __builtin_amdgcn_s_setprio(0);
        __builtin_amdgcn_sched_barrier(0);
        __builtin_amdgcn_s_barrier();
    }
}

// ================= fused QKV GEMM (128x128 tiles, flat grid 1536) ==============
// XCD-aware remap (T1): xcd = bid&7 owns 6 consecutive B-stripes (y), so the
// 32x m-direction re-reads of each 512KB weight stripe hit the local L2
// (6 stripes x 512KB = 3MB < 4MB/XCD).
__global__ __launch_bounds__(256, 4)
void gemm_qkv(const bfloat* __restrict__ A,
              const bfloat* __restrict__ Bq, const bfloat* __restrict__ Bk,
              const bfloat* __restrict__ Bv,
              const float* __restrict__ bq, const float* __restrict__ bk,
              const float* __restrict__ bv,
              bfloat* __restrict__ Qo, bfloat* __restrict__ Ko, bfloat* __restrict__ Vto,
              const float* __restrict__ cosT, const float* __restrict__ sinT) {
    constexpr int K = HH, N = HH;
    const int bid = blockIdx.x;
    const int xcd = bid & 7, idx = bid >> 3;       // idx 0..191
    const int by = xcd * 6 + (idx >> 5);           // 0..47
    const int bx = idx & 31;                       // 0..31
    const int sel = by >> 4;
    const bfloat* Bt = sel == 0 ? Bq : sel == 1 ? Bk : Bv;
    const float* bias = sel == 0 ? bq : sel == 1 ? bk : bv;
    const int m0 = bx * 128, n0 = (by & 15) * 128;

    f32x4 acc[4][4] = {};
    kloop128(A + (size_t)m0 * K, Bt + (size_t)n0 * K, acc);

    const int t = threadIdx.x, l = t & 63, lr = l & 15, lg = l >> 4;
    const int w = t >> 6, wm = (w >> 1) * 64, wc = w & 1;

    if (sel == 2) {   // V: write transposed (b, h, d, s)
#pragma unroll
        for (int mi = 0; mi < 4; mi++) {
            int row = m0 + wm + mi * 16 + lg * 4;
#pragma unroll
            for (int ni = 0; ni < 4; ni++) {
                int cb = wc * 32 + (ni & 1) * 16 + (ni >> 1) * 64;
                int col = n0 + cb + lr;
                float bv_ = bias[col];
#pragma unroll
                for (int j = 0; j < 4; j++) {
                    int r = row + j;
                    Vto[((size_t)((r >> 11) * HH + col)) * SS + (r & (SS - 1))] =
                        (bfloat)(acc[mi][ni][j] + bv_);
                }
            }
        }
    } else {          // Q/K: RoPE epilogue (Q also pre-scaled by 1/sqrt(DH))
        bfloat* C = sel == 0 ? Qo : Ko;
        const float qs = sel == 0 ? 0.088388347648318447f : 1.0f;
#pragma unroll
        for (int mi = 0; mi < 4; mi++) {
            int row = m0 + wm + mi * 16 + lg * 4;
#pragma unroll
            for (int ni = 0; ni < 2; ni++) {
                int d = wc * 32 + ni * 16 + lr;      // 0..63 within head
                int col1 = n0 + d, col2 = col1 + 64;
                float b1 = bias[col1], b2 = bias[col2];
#pragma unroll
                for (int j = 0; j < 4; j++) {
                    int r = row + j, s = r & (SS - 1);
                    float c  = cosT[s * 64 + d];
                    float sn = sinT[s * 64 + d];
                    float x1 = acc[mi][ni][j] + b1;
                    float x2 = acc[mi][ni + 2][j] + b2;
                    C[(size_t)r * N + col1] = (bfloat)((x1 * c - x2 * sn) * qs);
                    C[(size_t)r * N + col2] = (bfloat)((x2 * c + x1 * sn) * qs);
                }
            }
        }
    }
}

// ---------------- out-proj GEMM (128x128 tiles, flat grid 512, f32 out) --------
__global__ __launch_bounds__(256, 4)
void gemm_out(const bfloat* __restrict__ A, const bfloat* __restrict__ Bt,
              const float* __restrict__ bias, float* __restrict__ C) {
    constexpr int K = HH, N = HH;
    const int bid = blockIdx.x;
    const int xcd = bid & 7, idx = bid >> 3;       // idx 0..63
    const int by = xcd * 2 + (idx >> 5);           // 0..15
    const int bx = idx & 31;                       // 0..31
    const int m0 = bx * 128, n0 = by * 128;

    f32x4 acc[4][4] = {};
    kloop128(A + (size_t)m0 * K, Bt + (size_t)n0 * K, acc);

    const int t = threadIdx.x, l = t & 63, lr = l & 15, lg = l >> 4;
    const int w = t >> 6, wm = (w >> 1) * 64, wc = w & 1;
#pragma unroll
    for (int mi = 0; mi < 4; mi++) {
        int row = m0 + wm + mi * 16 + lg * 4;
#pragma unroll
        for (int ni = 0; ni < 4; ni++) {
            int cb = wc * 32 + (ni & 1) * 16 + (ni >> 1) * 64;
            int col = n0 + cb + lr;
            float bv = bias[col];
#pragma unroll
            for (int j = 0; j < 4; j++)
                C[(size_t)(row + j) * N + col] = acc[mi][ni][j] + bv;
        }
    }
}

// ---------------- Flash attention (causal), KVB=64, single-buffered LDS ----
__global__ __launch_bounds__(256, 4)
void attn_fwd(const bfloat* __restrict__ Q, const bfloat* __restrict__ K,
              const bfloat* __restrict__ Vt, bfloat* __restrict__ O) {
    __shared__ bfloat Ks[64 * 128];
    __shared__ bfloat Vs[128 * 64];
    __shared__ bfloat Pw[4][16 * 64];

    const int t = threadIdx.x, w = t >> 6, l = t & 63;
    const int lr = l & 15, lg = l >> 4;
    const int swz = (lr & 7) << 4;

    const int f = blockIdx.x;
    const int xcd = f & 7, slot = f >> 3;
    const int bh = xcd + 8 * (slot >> 5);
    const int qidx = 31 - (slot & 31);
    const int b = bh >> 4, h = bh & 15;
    const int q0 = qidx * 64 + w * 16;

    const size_t bo_ = (size_t)b * SS * HH + (size_t)h * DHH;
    const bfloat* Qp = Q + bo_;
    const bfloat* Kp = K + bo_;
    const bfloat* Vp = Vt + (size_t)(b * NHH + h) * DHH * SS;
    bfloat* Op = O + bo_;

    auto stage = [&](int kv0) {
#pragma unroll
        for (int i = 0; i < 4; i++) {
            int Ub = (i * 4 + w) * 64;
            int U = Ub + l;
            int r = U >> 4;
            int u = (U & 15) ^ (r & 7);
            gload_lds16(Kp + (size_t)(kv0 + r) * HH + u * 8, &Ks[Ub * 8]);
        }
#pragma unroll
        for (int i = 0; i < 4; i++) {
            int Ub = (i * 4 + w) * 64;
            int U = Ub + l;
            int r = U >> 3;
            int u = (U & 7) ^ (r & 7);
            gload_lds16(Vp + (size_t)r * SS + kv0 + u * 8, &Vs[Ub * 8]);
        }
    };

    bf16x8 qf[4];
#pragma unroll
    for (int kt = 0; kt < 4; kt++)
        qf[kt] = *reinterpret_cast<const bf16x8*>(Qp + (size_t)(q0 + lr) * HH + kt * 32 + lg * 8);

    bf16x8 ones;
#pragma unroll
    for (int e = 0; e < 8; e++) ones[e] = (bfloat)1.0f;

    f32x4 o[8] = {};
    f32x4 lsv = {};
    float m[4];
#pragma unroll
    for (int j = 0; j < 4; j++) m[j] = -1e30f;

    const int nkv = qidx + 1;

    for (int kv = 0; kv < nkv; ++kv) {
        stage(kv * 64);
        __syncthreads();

        const char* KB = (const char*)&Ks[0];
        const char* VB = (const char*)&Vs[0];

        f32x4 sc[4] = {};
        __builtin_amdgcn_s_setprio(1);
#pragma unroll
        for (int kt = 0; kt < 4; kt++) {
            const int col = (kt * 64 + lg * 16);
#pragma unroll
            for (int kb = 0; kb < 4; kb++) {
                bf16x8 kf = *reinterpret_cast<const bf16x8*>(
                    KB + (kb * 16 + lr) * 256 + (col ^ swz));
                sc[kb] = mfma16(qf[kt], kf, sc[kb]);
            }
        }
        __builtin_amdgcn_s_setprio(0);

        const bool diag = (kv == nkv - 1);
        float p[4][4], alpha[4];
        bool ga = false;
#pragma unroll
        for (int j = 0; j < 4; j++) {
            float v0 = sc[0][j], v1 = sc[1][j], v2 = sc[2][j], v3 = sc[3][j];
            if (diag) {
                int qr = q0 + lg * 4 + j;
                int k0 = kv * 64 + lr;
                if (k0      > qr) v0 = -1e30f;
                if (k0 + 16 > qr) v1 = -1e30f;
                if (k0 + 32 > qr) v2 = -1e30f;
                if (k0 + 48 > qr) v3 = -1e30f;
            }
            float mx = rowmax16(fmaxf(fmaxf(v0, v1), fmaxf(v2, v3)));
            bool grow = mx > m[j] + 8.0f;
            float mn = grow ? mx : m[j];
            alpha[j] = grow ? __expf(m[j] - mn) : 1.0f;
            m[j] = mn;
            ga = ga || grow;
            p[0][j] = __expf(v0 - mn);
            p[1][j] = __expf(v1 - mn);
            p[2][j] = __expf(v2 - mn);
            p[3][j] = __expf(v3 - mn);
        }
        if (__any(ga)) {
#pragma unroll
            for (int j = 0; j < 4; j++) {
                lsv[j] *= alpha[j];
#pragma unroll
                for (int nt = 0; nt < 8; nt++) o[nt][j] *= alpha[j];
            }
        }

        char* pwb = (char*)&Pw[w][0];
#pragma unroll
        for (int j = 0; j < 4; j++) {
            int q = lg * 4 + j;
            int qs = (q & 7) << 4;
#pragma unroll
            for (int kb = 0; kb < 4; kb++)
                *(bfloat*)(pwb + q * 128 + ((kb * 32 + lr * 2) ^ qs)) = (bfloat)p[kb][j];
        }
        asm volatile("s_waitcnt lgkmcnt(0)" ::: "memory");
        __builtin_amdgcn_sched_barrier(0);

        const char* pwr = (const char*)&Pw[w][0];
        bf16x8 pa0 = *reinterpret_cast<const bf16x8*>(pwr + lr * 128 + ((lg * 16) ^ swz));
        bf16x8 pa1 = *reinterpret_cast<const bf16x8*>(pwr + lr * 128 + ((64 + lg * 16) ^ swz));
        __builtin_amdgcn_s_setprio(1);
        lsv = mfma16(pa0, ones, lsv);
        lsv = mfma16(pa1, ones, lsv);
#pragma unroll
        for (int nt = 0; nt < 8; nt++) {
            const char* vb = VB + (nt * 16 + lr) * 128;
            bf16x8 vf0 = *reinterpret_cast<const bf16x8*>(vb + ((lg * 16) ^ swz));
            bf16x8 vf1 = *reinterpret_cast<const bf16x8*>(vb + ((64 + lg * 16) ^ swz));
            o[nt] = mfma16(pa0, vf0, o[nt]);
            o[nt] = mfma16(pa1, vf1, o[nt]);
        }
        __builtin_amdgcn_s_setprio(0);
        __syncthreads();
    }

#pragma unroll
    for (int j = 0; j < 4; j++) {
        float inv = 1.0f / lsv[j];
        int row = q0 + lg * 4 + j;
#pragma unroll
        for (int nt = 0; nt < 8; nt++)
            Op[(size_t)row * HH + nt * 16 + lr] = (bfloat)(o[nt][j] * inv);
    }
}

// ---------------- launch ----------------
extern "C" void kernel_launch(void* const* d_in, const int* in_sizes, int n_in,
                              void* d_out, int out_size, void* d_ws, size_t ws_size,
                              hipStream_t stream) {
    (void)in_sizes; (void)n_in; (void)out_size; (void)ws_size;
    const float* hs = (const float*)d_in[0];
    const float* Wq = (const float*)d_in[2];
    const float* bq = (const float*)d_in[3];
    const float* Wk = (const float*)d_in[4];
    const float* bk = (const float*)d_in[5];
    const float* Wv = (const float*)d_in[6];
    const float* bv = (const float*)d_in[7];
    const float* Wo = (const float*)d_in[8];
    const float* bo = (const float*)d_in[9];

    char* ws = (char*)d_ws;
    size_t off = 0;
    auto alloc = [&](size_t bytes) { void* p = ws + off; off += (bytes + 255) & ~(size_t)255; return p; };
    const size_t MK = (size_t)BB * SS * HH;   // 8M elems
    const size_t NK = (size_t)HH * HH;        // 4M elems

    bfloat* Xb  = (bfloat*)alloc(MK * 2);
    bfloat* Wqb = (bfloat*)alloc(NK * 2);
    bfloat* Wkb = (bfloat*)alloc(NK * 2);
    bfloat* Wvb = (bfloat*)alloc(NK * 2);
    bfloat* Wob = (bfloat*)alloc(NK * 2);
    bfloat* Qb  = (bfloat*)alloc(MK * 2);
    bfloat* Kb  = (bfloat*)alloc(MK * 2);
    bfloat* Vtb = (bfloat*)alloc(MK * 2);     // (b, h, d, s)
    float*  cosT = (float*)alloc((size_t)SS * 64 * 4);
    float*  sinT = (float*)alloc((size_t)SS * 64 * 4);
    bfloat* AOb = Xb;   // reuse: X no longer needed after QKV GEMM

    prep_all<<<8192 + 16384 + 512, 256, 0, stream>>>(
        hs, Wq, Wk, Wv, Wo, Xb, Wqb, Wkb, Wvb, Wob, cosT, sinT);

    gemm_qkv<<<1536, 256, 0, stream>>>(
        Xb, Wqb, Wkb, Wvb, bq, bk, bv, Qb, Kb, Vtb, cosT, sinT);

    attn_fwd<<<1024, 256, 0, stream>>>(Qb, Kb, Vtb, AOb);

    gemm_out<<<512, 256, 0, stream>>>(AOb, Wob, bo, (float*)d_out);
}

// Round 12
// 308.119 us; speedup vs baseline: 1.0664x; 1.0161x over previous
//
#include <hip/hip_runtime.h>
#include <hip/hip_bf16.h>
#include <cstdint>
#include <cstddef>

#define BB 2
#define SS 2048
#define HH 2048
#define NHH 16
#define DHH 128

using f32x4  = __attribute__((ext_vector_type(4))) float;
using bf16x8 = __attribute__((ext_vector_type(8))) __bf16;
using bf16x4 = __attribute__((ext_vector_type(4))) __bf16;
using bfloat = __bf16;

__device__ inline void gload_lds16(const void* g, void* l) {
    __builtin_amdgcn_global_load_lds(
        (const __attribute__((address_space(1))) void*)g,
        (__attribute__((address_space(3))) void*)l, 16, 0, 0);
}

__device__ inline f32x4 mfma16(bf16x8 a, bf16x8 b, f32x4 c) {
    return __builtin_amdgcn_mfma_f32_16x16x32_bf16(a, b, c, 0, 0, 0);
}

template <int CTRL>
__device__ inline float dpp_max_step(float x) {
    int y = __builtin_amdgcn_update_dpp(0, __builtin_bit_cast(int, x), CTRL, 0xf, 0xf, false);
    return fmaxf(x, __builtin_bit_cast(float, y));
}
__device__ inline float rowmax16(float x) {
    x = dpp_max_step<0x121>(x);
    x = dpp_max_step<0x122>(x);
    x = dpp_max_step<0x124>(x);
    x = dpp_max_step<0x128>(x);
    return x;
}

// -------- merged prep: X cvt (8192 blk) + 4 weight cvts (16384 blk) + rope (512 blk)
__global__ void prep_all(const float* __restrict__ hs,
                         const float* __restrict__ w0, const float* __restrict__ w1,
                         const float* __restrict__ w2, const float* __restrict__ w3,
                         bfloat* __restrict__ xb,
                         bfloat* __restrict__ d0, bfloat* __restrict__ d1,
                         bfloat* __restrict__ d2, bfloat* __restrict__ d3,
                         float* __restrict__ cosT, float* __restrict__ sinT) {
    const int bid = blockIdx.x, tid = threadIdx.x;
    if (bid < 8192 + 16384) {
        const float* s;
        bfloat* d;
        int i;
        if (bid < 8192) {
            s = hs; d = xb; i = bid * 256 + tid;
        } else {
            int b2 = bid - 8192, sel = b2 >> 12;
            s = sel == 0 ? w0 : sel == 1 ? w1 : sel == 2 ? w2 : w3;
            d = sel == 0 ? d0 : sel == 1 ? d1 : sel == 2 ? d2 : d3;
            i = (b2 & 4095) * 256 + tid;
        }
        float4 v = reinterpret_cast<const float4*>(s)[i];
        bf16x4 o;
        o[0] = (bfloat)v.x; o[1] = (bfloat)v.y; o[2] = (bfloat)v.z; o[3] = (bfloat)v.w;
        reinterpret_cast<bf16x4*>(d)[i] = o;
    } else {
        int i = (bid - 24576) * 256 + tid;      // 0 .. SS*64-1
        int s = i >> 6, j = i & 63;
        float invf = powf(10000.0f, -(float)j / 64.0f);
        float ang = (float)s * invf;
        cosT[i] = cosf(ang);
        sinT[i] = sinf(ang);
    }
}

// ======== 128x128 tile K-loop, BK=32, 4 waves, 2-phase double-buffered ========
// (R8 verbatim -- best measured GEMM core.)
__device__ __forceinline__ void kloop128(const bfloat* __restrict__ Ag,
                                         const bfloat* __restrict__ Bg,
                                         f32x4 (&acc)[4][4]) {
    constexpr int K = HH, NT = K / 32;
    __shared__ bfloat As[2][128 * 32];
    __shared__ bfloat Bs[2][128 * 32];
    const int t = threadIdx.x, l = t & 63, lr = l & 15, lg = l >> 4;
    const int w = t >> 6, wm = (w >> 1) * 64, wc = w & 1;
    const int ubase = t & ~63;

    auto stage = [&](int buf, int kt) {
#pragma unroll
        for (int i = 0; i < 2; i++) {
            int idx = i * 256 + t;
            int r = idx >> 2, u = idx & 3;
            int us = u ^ (r & 3) ^ ((r >> 2) & 1);
            gload_lds16(Ag + (size_t)r * K + kt * 32 + us * 8,
                        &As[buf][(i * 256 + ubase) * 8]);
        }
#pragma unroll
        for (int i = 0; i < 2; i++) {
            int idx = i * 256 + t;
            int r = idx >> 2, u = idx & 3;
            int us = u ^ (r & 3) ^ ((r >> 2) & 1);
            gload_lds16(Bg + (size_t)r * K + kt * 32 + us * 8,
                        &Bs[buf][(i * 256 + ubase) * 8]);
        }
    };

    stage(0, 0);

#pragma unroll 1
    for (int kt = 0; kt < NT; ++kt) {
        const int buf = kt & 1;
        if (kt + 1 < NT) {
            stage(buf ^ 1, kt + 1);
            asm volatile("s_waitcnt vmcnt(4)" ::: "memory");
        } else {
            asm volatile("s_waitcnt vmcnt(0)" ::: "memory");
        }
        __builtin_amdgcn_s_barrier();
        __builtin_amdgcn_sched_barrier(0);

        const bfloat* A_ = As[buf];
        const bfloat* B_ = Bs[buf];
        bf16x8 af[4], bfr[4];
#pragma unroll
        for (int mi = 0; mi < 4; mi++) {
            int row = wm + mi * 16 + lr;
            int us = lg ^ (row & 3) ^ ((row >> 2) & 1);
            af[mi] = *reinterpret_cast<const bf16x8*>(&A_[row * 32 + us * 8]);
        }
#pragma unroll
        for (int ni = 0; ni < 4; ni++) {
            int row = wc * 32 + (ni & 1) * 16 + (ni >> 1) * 64 + lr;
            int us = lg ^ (row & 3) ^ ((row >> 2) & 1);
            bfr[ni] = *reinterpret_cast<const bf16x8*>(&B_[row * 32 + us * 8]);
        }
        __builtin_amdgcn_s_setprio(1);
#pragma unroll
        for (int mi = 0; mi < 4; mi++)
#pragma unroll
            for (int ni = 0; ni < 4; ni++)
                acc[mi][ni] = mfma16(af[mi], bfr[ni], acc[mi][ni]);
        __builtin_amdgcn_s_setprio(0);
        __builtin_amdgcn_sched_barrier(0);
        __builtin_amdgcn_s_barrier();
    }
}

// ================= fused QKV GEMM (128x128 tiles, 256 threads) =================
// grid (32, 48): blockIdx.y>>4 selects {Q, K, V}.
__global__ __launch_bounds__(256, 4)
void gemm_qkv(const bfloat* __restrict__ A,
              const bfloat* __restrict__ Bq, const bfloat* __restrict__ Bk,
              const bfloat* __restrict__ Bv,
              const float* __restrict__ bq, const float* __restrict__ bk,
              const float* __restrict__ bv,
              bfloat* __restrict__ Qo, bfloat* __restrict__ Ko, bfloat* __restrict__ Vto,
              const float* __restrict__ cosT, const float* __restrict__ sinT) {
    constexpr int K = HH, N = HH;
    const int sel = blockIdx.y >> 4;
    const bfloat* Bt = sel == 0 ? Bq : sel == 1 ? Bk : Bv;
    const float* bias = sel == 0 ? bq : sel == 1 ? bk : bv;
    const int m0 = blockIdx.x * 128, n0 = (blockIdx.y & 15) * 128;

    f32x4 acc[4][4] = {};
    kloop128(A + (size_t)m0 * K, Bt + (size_t)n0 * K, acc);

    const int t = threadIdx.x, l = t & 63, lr = l & 15, lg = l >> 4;
    const int w = t >> 6, wm = (w >> 1) * 64, wc = w & 1;

    if (sel == 2) {   // V: write transposed (b, h, d, s) -- j-packed ushort4 stores
#pragma unroll
        for (int mi = 0; mi < 4; mi++) {
            int row = m0 + wm + mi * 16 + lg * 4;      // row % 4 == 0
            int bb = row >> 11;
            int s0 = row & (SS - 1);
#pragma unroll
            for (int ni = 0; ni < 4; ni++) {
                int cb = wc * 32 + (ni & 1) * 16 + (ni >> 1) * 64;
                int col = n0 + cb + lr;
                float bv_ = bias[col];
                bf16x4 pack;
#pragma unroll
                for (int j = 0; j < 4; j++)
                    pack[j] = (bfloat)(acc[mi][ni][j] + bv_);
                *reinterpret_cast<bf16x4*>(
                    &Vto[((size_t)(bb * HH + col)) * SS + s0]) = pack;
            }
        }
    } else {          // Q/K: RoPE epilogue (Q also pre-scaled by 1/sqrt(DH))
        bfloat* C = sel == 0 ? Qo : Ko;
        const float qs = sel == 0 ? 0.088388347648318447f : 1.0f;
#pragma unroll
        for (int mi = 0; mi < 4; mi++) {
            int row = m0 + wm + mi * 16 + lg * 4;
#pragma unroll
            for (int ni = 0; ni < 2; ni++) {
                int d = wc * 32 + ni * 16 + lr;      // 0..63 within head
                int col1 = n0 + d, col2 = col1 + 64;
                float b1 = bias[col1], b2 = bias[col2];
#pragma unroll
                for (int j = 0; j < 4; j++) {
                    int r = row + j, s = r & (SS - 1);
                    float c  = cosT[s * 64 + d];
                    float sn = sinT[s * 64 + d];
                    float x1 = acc[mi][ni][j] + b1;
                    float x2 = acc[mi][ni + 2][j] + b2;
                    C[(size_t)r * N + col1] = (bfloat)((x1 * c - x2 * sn) * qs);
                    C[(size_t)r * N + col2] = (bfloat)((x2 * c + x1 * sn) * qs);
                }
            }
        }
    }
}

// ---------------- out-proj GEMM (128x128 tiles, f32 out) ----------------
__global__ __launch_bounds__(256, 4)
void gemm_out(const bfloat* __restrict__ A, const bfloat* __restrict__ Bt,
              const float* __restrict__ bias, float* __restrict__ C) {
    constexpr int K = HH, N = HH;
    const int m0 = blockIdx.x * 128, n0 = blockIdx.y * 128;

    f32x4 acc[4][4] = {};
    kloop128(A + (size_t)m0 * K, Bt + (size_t)n0 * K, acc);

    const int t = threadIdx.x, l = t & 63, lr = l & 15, lg = l >> 4;
    const int w = t >> 6, wm = (w >> 1) * 64, wc = w & 1;
#pragma unroll
    for (int mi = 0; mi < 4; mi++) {
        int row = m0 + wm + mi * 16 + lg * 4;
#pragma unroll
        for (int ni = 0; ni < 4; ni++) {
            int cb = wc * 32 + (ni & 1) * 16 + (ni >> 1) * 64;
            int col = n0 + cb + lr;
            float bv = bias[col];
#pragma unroll
            for (int j = 0; j < 4; j++)
                C[(size_t)(row + j) * N + col] = acc[mi][ni][j] + bv;
        }
    }
}

// ---------------- Flash attention (causal), KVB=64, single-buffered LDS ----
__global__ __launch_bounds__(256, 4)
void attn_fwd(const bfloat* __restrict__ Q, const bfloat* __restrict__ K,
              const bfloat* __restrict__ Vt, bfloat* __restrict__ O) {
    __shared__ bfloat Ks[64 * 128];
    __shared__ bfloat Vs[128 * 64];
    __shared__ bfloat Pw[4][16 * 64];

    const int t = threadIdx.x, w = t >> 6, l = t & 63;
    const int lr = l & 15, lg = l >> 4;
    const int swz = (lr & 7) << 4;

    const int f = blockIdx.x;
    const int xcd = f & 7, slot = f >> 3;
    const int bh = xcd + 8 * (slot >> 5);
    const int qidx = 31 - (slot & 31);
    const int b = bh >> 4, h = bh & 15;
    const int q0 = qidx * 64 + w * 16;

    const size_t bo_ = (size_t)b * SS * HH + (size_t)h * DHH;
    const bfloat* Qp = Q + bo_;
    const bfloat* Kp = K + bo_;
    const bfloat* Vp = Vt + (size_t)(b * NHH + h) * DHH * SS;
    bfloat* Op = O + bo_;

    auto stage = [&](int kv0) {
#pragma unroll
        for (int i = 0; i < 4; i++) {
            int Ub = (i * 4 + w) * 64;
            int U = Ub + l;
            int r = U >> 4;
            int u = (U & 15) ^ (r & 7);
            gload_lds16(Kp + (size_t)(kv0 + r) * HH + u * 8, &Ks[Ub * 8]);
        }
#pragma unroll
        for (int i = 0; i < 4; i++) {
            int Ub = (i * 4 + w) * 64;
            int U = Ub + l;
            int r = U >> 3;
            int u = (U & 7) ^ (r & 7);
            gload_lds16(Vp + (size_t)r * SS + kv0 + u * 8, &Vs[Ub * 8]);
        }
    };

    bf16x8 qf[4];
#pragma unroll
    for (int kt = 0; kt < 4; kt++)
        qf[kt] = *reinterpret_cast<const bf16x8*>(Qp + (size_t)(q0 + lr) * HH + kt * 32 + lg * 8);

    bf16x8 ones;
#pragma unroll
    for (int e = 0; e < 8; e++) ones[e] = (bfloat)1.0f;

    f32x4 o[8] = {};
    f32x4 lsv = {};
    float m[4];
#pragma unroll
    for (int j = 0; j < 4; j++) m[j] = -1e30f;

    const int nkv = qidx + 1;

    for (int kv = 0; kv < nkv; ++kv) {
        stage(kv * 64);
        __syncthreads();

        const char* KB = (const char*)&Ks[0];
        const char* VB = (const char*)&Vs[0];

        f32x4 sc[4] = {};
        __builtin_amdgcn_s_setprio(1);
#pragma unroll
        for (int kt = 0; kt < 4; kt++) {
            const int col = (kt * 64 + lg * 16);
#pragma unroll
            for (int kb = 0; kb < 4; kb++) {
                bf16x8 kf = *reinterpret_cast<const bf16x8*>(
                    KB + (kb * 16 + lr) * 256 + (col ^ swz));
                sc[kb] = mfma16(qf[kt], kf, sc[kb]);
            }
        }
        __builtin_amdgcn_s_setprio(0);

        const bool diag = (kv == nkv - 1);
        float p[4][4], alpha[4];
        bool ga = false;
#pragma unroll
        for (int j = 0; j < 4; j++) {
            float v0 = sc[0][j], v1 = sc[1][j], v2 = sc[2][j], v3 = sc[3][j];
            if (diag) {
                int qr = q0 + lg * 4 + j;
                int k0 = kv * 64 + lr;
                if (k0      > qr) v0 = -1e30f;
                if (k0 + 16 > qr) v1 = -1e30f;
                if (k0 + 32 > qr) v2 = -1e30f;
                if (k0 + 48 > qr) v3 = -1e30f;
            }
            float mx = rowmax16(fmaxf(fmaxf(v0, v1), fmaxf(v2, v3)));
            bool grow = mx > m[j] + 8.0f;
            float mn = grow ? mx : m[j];
            alpha[j] = grow ? __expf(m[j] - mn) : 1.0f;
            m[j] = mn;
            ga = ga || grow;
            p[0][j] = __expf(v0 - mn);
            p[1][j] = __expf(v1 - mn);
            p[2][j] = __expf(v2 - mn);
            p[3][j] = __expf(v3 - mn);
        }
        if (__any(ga)) {
#pragma unroll
            for (int j = 0; j < 4; j++) {
                lsv[j] *= alpha[j];
#pragma unroll
                for (int nt = 0; nt < 8; nt++) o[nt][j] *= alpha[j];
            }
        }

        char* pwb = (char*)&Pw[w][0];
#pragma unroll
        for (int j = 0; j < 4; j++) {
            int q = lg * 4 + j;
            int qs = (q & 7) << 4;
#pragma unroll
            for (int kb = 0; kb < 4; kb++)
                *(bfloat*)(pwb + q * 128 + ((kb * 32 + lr * 2) ^ qs)) = (bfloat)p[kb][j];
        }
        asm volatile("s_waitcnt lgkmcnt(0)" ::: "memory");
        __builtin_amdgcn_sched_barrier(0);

        const char* pwr = (const char*)&Pw[w][0];
        bf16x8 pa0 = *reinterpret_cast<const bf16x8*>(pwr + lr * 128 + ((lg * 16) ^ swz));
        bf16x8 pa1 = *reinterpret_cast<const bf16x8*>(pwr + lr * 128 + ((64 + lg * 16) ^ swz));
        __builtin_amdgcn_s_setprio(1);
        lsv = mfma16(pa0, ones, lsv);
        lsv = mfma16(pa1, ones, lsv);
#pragma unroll
        for (int nt = 0; nt < 8; nt++) {
            const char* vb = VB + (nt * 16 + lr) * 128;
            bf16x8 vf0 = *reinterpret_cast<const bf16x8*>(vb + ((lg * 16) ^ swz));
            bf16x8 vf1 = *reinterpret_cast<const bf16x8*>(vb + ((64 + lg * 16) ^ swz));
            o[nt] = mfma16(pa0, vf0, o[nt]);
            o[nt] = mfma16(pa1, vf1, o[nt]);
        }
        __builtin_amdgcn_s_setprio(0);
        __syncthreads();
    }

#pragma unroll
    for (int j = 0; j < 4; j++) {
        float inv = 1.0f / lsv[j];
        int row = q0 + lg * 4 + j;
#pragma unroll
        for (int nt = 0; nt < 8; nt++)
            Op[(size_t)row * HH + nt * 16 + lr] = (bfloat)(o[nt][j] * inv);
    }
}

// ---------------- launch ----------------
extern "C" void kernel_launch(void* const* d_in, const int* in_sizes, int n_in,
                              void* d_out, int out_size, void* d_ws, size_t ws_size,
                              hipStream_t stream) {
    (void)in_sizes; (void)n_in; (void)out_size; (void)ws_size;
    const float* hs = (const float*)d_in[0];
    const float* Wq = (const float*)d_in[2];
    const float* bq = (const float*)d_in[3];
    const float* Wk = (const float*)d_in[4];
    const float* bk = (const float*)d_in[5];
    const float* Wv = (const float*)d_in[6];
    const float* bv = (const float*)d_in[7];
    const float* Wo = (const float*)d_in[8];
    const float* bo = (const float*)d_in[9];

    char* ws = (char*)d_ws;
    size_t off = 0;
    auto alloc = [&](size_t bytes) { void* p = ws + off; off += (bytes + 255) & ~(size_t)255; return p; };
    const size_t MK = (size_t)BB * SS * HH;   // 8M elems
    const size_t NK = (size_t)HH * HH;        // 4M elems

    bfloat* Xb  = (bfloat*)alloc(MK * 2);
    bfloat* Wqb = (bfloat*)alloc(NK * 2);
    bfloat* Wkb = (bfloat*)alloc(NK * 2);
    bfloat* Wvb = (bfloat*)alloc(NK * 2);
    bfloat* Wob = (bfloat*)alloc(NK * 2);
    bfloat* Qb  = (bfloat*)alloc(MK * 2);
    bfloat* Kb  = (bfloat*)alloc(MK * 2);
    bfloat* Vtb = (bfloat*)alloc(MK * 2);     // (b, h, d, s)
    float*  cosT = (float*)alloc((size_t)SS * 64 * 4);
    float*  sinT = (float*)alloc((size_t)SS * 64 * 4);
    bfloat* AOb = Xb;   // reuse: X no longer needed after QKV GEMM

    prep_all<<<8192 + 16384 + 512, 256, 0, stream>>>(
        hs, Wq, Wk, Wv, Wo, Xb, Wqb, Wkb, Wvb, Wob, cosT, sinT);

    gemm_qkv<<<dim3(32, 48), 256, 0, stream>>>(
        Xb, Wqb, Wkb, Wvb, bq, bk, bv, Qb, Kb, Vtb, cosT, sinT);

    attn_fwd<<<1024, 256, 0, stream>>>(Qb, Kb, Vtb, AOb);

    gemm_out<<<dim3(32, 16), 256, 0, stream>>>(AOb, Wob, bo, (float*)d_out);
}

// Round 13
// 307.649 us; speedup vs baseline: 1.0681x; 1.0015x over previous
//
#include <hip/hip_runtime.h>
#include <hip/hip_bf16.h>
#include <cstdint>
#include <cstddef>

#define BB 2
#define SS 2048
#define HH 2048
#define NHH 16
#define DHH 128

using f32x4  = __attribute__((ext_vector_type(4))) float;
using bf16x8 = __attribute__((ext_vector_type(8))) __bf16;
using bf16x4 = __attribute__((ext_vector_type(4))) __bf16;
using bfloat = __bf16;

__device__ inline void gload_lds16(const void* g, void* l) {
    __builtin_amdgcn_global_load_lds(
        (const __attribute__((address_space(1))) void*)g,
        (__attribute__((address_space(3))) void*)l, 16, 0, 0);
}

__device__ inline f32x4 mfma16(bf16x8 a, bf16x8 b, f32x4 c) {
    return __builtin_amdgcn_mfma_f32_16x16x32_bf16(a, b, c, 0, 0, 0);
}

template <int CTRL>
__device__ inline float dpp_max_step(float x) {
    int y = __builtin_amdgcn_update_dpp(0, __builtin_bit_cast(int, x), CTRL, 0xf, 0xf, false);
    return fmaxf(x, __builtin_bit_cast(float, y));
}
__device__ inline float rowmax16(float x) {
    x = dpp_max_step<0x121>(x);
    x = dpp_max_step<0x122>(x);
    x = dpp_max_step<0x124>(x);
    x = dpp_max_step<0x128>(x);
    return x;
}

// -------- merged prep: X cvt (8192 blk) + 4 weight cvts (16384 blk) + rope (512 blk)
__global__ void prep_all(const float* __restrict__ hs,
                         const float* __restrict__ w0, const float* __restrict__ w1,
                         const float* __restrict__ w2, const float* __restrict__ w3,
                         bfloat* __restrict__ xb,
                         bfloat* __restrict__ d0, bfloat* __restrict__ d1,
                         bfloat* __restrict__ d2, bfloat* __restrict__ d3,
                         float* __restrict__ cosT, float* __restrict__ sinT) {
    const int bid = blockIdx.x, tid = threadIdx.x;
    if (bid < 8192 + 16384) {
        const float* s;
        bfloat* d;
        int i;
        if (bid < 8192) {
            s = hs; d = xb; i = bid * 256 + tid;
        } else {
            int b2 = bid - 8192, sel = b2 >> 12;
            s = sel == 0 ? w0 : sel == 1 ? w1 : sel == 2 ? w2 : w3;
            d = sel == 0 ? d0 : sel == 1 ? d1 : sel == 2 ? d2 : d3;
            i = (b2 & 4095) * 256 + tid;
        }
        float4 v = reinterpret_cast<const float4*>(s)[i];
        bf16x4 o;
        o[0] = (bfloat)v.x; o[1] = (bfloat)v.y; o[2] = (bfloat)v.z; o[3] = (bfloat)v.w;
        reinterpret_cast<bf16x4*>(d)[i] = o;
    } else {
        int i = (bid - 24576) * 256 + tid;      // 0 .. SS*64-1
        int s = i >> 6, j = i & 63;
        float invf = powf(10000.0f, -(float)j / 64.0f);
        float ang = (float)s * invf;
        cosT[i] = cosf(ang);
        sinT[i] = sinf(ang);
    }
}

// ======== 128x128 tile K-loop, BK=32, 4 waves, ONE barrier per K-tile ==========
// 2 buffers, 32KB, 4 blocks/CU.  Per tile: {vmcnt(0) [own staged loads landed];
// s_barrier [all waves' loads landed AND all waves' prev-tile reads done];
// stage(kt+1 -> buf^1) [WAR-safe: buf^1's readers finished before this barrier];
// ds_read frags(buf); MFMA}.  Halves barrier count vs the classic 2-barrier
// loop -- the end-of-tile barrier's protection is subsumed by the next tile's
// top barrier.  Swizzle u' = u ^ (r&3) ^ ((r>>2)&1) both-sides (2-way frag reads).
__device__ __forceinline__ void kloop128(const bfloat* __restrict__ Ag,
                                         const bfloat* __restrict__ Bg,
                                         f32x4 (&acc)[4][4]) {
    constexpr int K = HH, NT = K / 32;
    __shared__ bfloat As[2][128 * 32];
    __shared__ bfloat Bs[2][128 * 32];
    const int t = threadIdx.x, l = t & 63, lr = l & 15, lg = l >> 4;
    const int w = t >> 6, wm = (w >> 1) * 64, wc = w & 1;
    const int ubase = t & ~63;

    auto stage = [&](int buf, int kt) {
#pragma unroll
        for (int i = 0; i < 2; i++) {
            int idx = i * 256 + t;
            int r = idx >> 2, u = idx & 3;
            int us = u ^ (r & 3) ^ ((r >> 2) & 1);
            gload_lds16(Ag + (size_t)r * K + kt * 32 + us * 8,
                        &As[buf][(i * 256 + ubase) * 8]);
        }
#pragma unroll
        for (int i = 0; i < 2; i++) {
            int idx = i * 256 + t;
            int r = idx >> 2, u = idx & 3;
            int us = u ^ (r & 3) ^ ((r >> 2) & 1);
            gload_lds16(Bg + (size_t)r * K + kt * 32 + us * 8,
                        &Bs[buf][(i * 256 + ubase) * 8]);
        }
    };

    stage(0, 0);

#pragma unroll 1
    for (int kt = 0; kt < NT; ++kt) {
        const int buf = kt & 1;
        asm volatile("s_waitcnt vmcnt(0)" ::: "memory");   // own stage(kt) landed
        __builtin_amdgcn_s_barrier();                      // all landed; prev reads done
        __builtin_amdgcn_sched_barrier(0);
        if (kt + 1 < NT) stage(buf ^ 1, kt + 1);           // overlaps this tile's compute

        const bfloat* A_ = As[buf];
        const bfloat* B_ = Bs[buf];
        bf16x8 af[4], bfr[4];
#pragma unroll
        for (int mi = 0; mi < 4; mi++) {
            int row = wm + mi * 16 + lr;
            int us = lg ^ (row & 3) ^ ((row >> 2) & 1);
            af[mi] = *reinterpret_cast<const bf16x8*>(&A_[row * 32 + us * 8]);
        }
#pragma unroll
        for (int ni = 0; ni < 4; ni++) {
            int row = wc * 32 + (ni & 1) * 16 + (ni >> 1) * 64 + lr;
            int us = lg ^ (row & 3) ^ ((row >> 2) & 1);
            bfr[ni] = *reinterpret_cast<const bf16x8*>(&B_[row * 32 + us * 8]);
        }
        __builtin_amdgcn_s_setprio(1);
#pragma unroll
        for (int mi = 0; mi < 4; mi++)
#pragma unroll
            for (int ni = 0; ni < 4; ni++)
                acc[mi][ni] = mfma16(af[mi], bfr[ni], acc[mi][ni]);
        __builtin_amdgcn_s_setprio(0);
        __builtin_amdgcn_sched_barrier(0);
    }
}

// ================= fused QKV GEMM (128x128 tiles, 256 threads) =================
// grid (32, 48): blockIdx.y>>4 selects {Q, K, V}.
__global__ __launch_bounds__(256, 4)
void gemm_qkv(const bfloat* __restrict__ A,
              const bfloat* __restrict__ Bq, const bfloat* __restrict__ Bk,
              const bfloat* __restrict__ Bv,
              const float* __restrict__ bq, const float* __restrict__ bk,
              const float* __restrict__ bv,
              bfloat* __restrict__ Qo, bfloat* __restrict__ Ko, bfloat* __restrict__ Vto,
              const float* __restrict__ cosT, const float* __restrict__ sinT) {
    constexpr int K = HH, N = HH;
    const int sel = blockIdx.y >> 4;
    const bfloat* Bt = sel == 0 ? Bq : sel == 1 ? Bk : Bv;
    const float* bias = sel == 0 ? bq : sel == 1 ? bk : bv;
    const int m0 = blockIdx.x * 128, n0 = (blockIdx.y & 15) * 128;

    f32x4 acc[4][4] = {};
    kloop128(A + (size_t)m0 * K, Bt + (size_t)n0 * K, acc);

    const int t = threadIdx.x, l = t & 63, lr = l & 15, lg = l >> 4;
    const int w = t >> 6, wm = (w >> 1) * 64, wc = w & 1;

    if (sel == 2) {   // V: write transposed (b, h, d, s) -- j-packed stores
#pragma unroll
        for (int mi = 0; mi < 4; mi++) {
            int row = m0 + wm + mi * 16 + lg * 4;      // row % 4 == 0
            int bb = row >> 11;
            int s0 = row & (SS - 1);
#pragma unroll
            for (int ni = 0; ni < 4; ni++) {
                int cb = wc * 32 + (ni & 1) * 16 + (ni >> 1) * 64;
                int col = n0 + cb + lr;
                float bv_ = bias[col];
                bf16x4 pack;
#pragma unroll
                for (int j = 0; j < 4; j++)
                    pack[j] = (bfloat)(acc[mi][ni][j] + bv_);
                *reinterpret_cast<bf16x4*>(
                    &Vto[((size_t)(bb * HH + col)) * SS + s0]) = pack;
            }
        }
    } else {          // Q/K: RoPE epilogue (Q also pre-scaled by 1/sqrt(DH))
        bfloat* C = sel == 0 ? Qo : Ko;
        const float qs = sel == 0 ? 0.088388347648318447f : 1.0f;
#pragma unroll
        for (int mi = 0; mi < 4; mi++) {
            int row = m0 + wm + mi * 16 + lg * 4;
#pragma unroll
            for (int ni = 0; ni < 2; ni++) {
                int d = wc * 32 + ni * 16 + lr;      // 0..63 within head
                int col1 = n0 + d, col2 = col1 + 64;
                float b1 = bias[col1], b2 = bias[col2];
#pragma unroll
                for (int j = 0; j < 4; j++) {
                    int r = row + j, s = r & (SS - 1);
                    float c  = cosT[s * 64 + d];
                    float sn = sinT[s * 64 + d];
                    float x1 = acc[mi][ni][j] + b1;
                    float x2 = acc[mi][ni + 2][j] + b2;
                    C[(size_t)r * N + col1] = (bfloat)((x1 * c - x2 * sn) * qs);
                    C[(size_t)r * N + col2] = (bfloat)((x2 * c + x1 * sn) * qs);
                }
            }
        }
    }
}

// ---------------- out-proj GEMM (128x128 tiles, f32 out) ----------------
__global__ __launch_bounds__(256, 4)
void gemm_out(const bfloat* __restrict__ A, const bfloat* __restrict__ Bt,
              const float* __restrict__ bias, float* __restrict__ C) {
    constexpr int K = HH, N = HH;
    const int m0 = blockIdx.x * 128, n0 = blockIdx.y * 128;

    f32x4 acc[4][4] = {};
    kloop128(A + (size_t)m0 * K, Bt + (size_t)n0 * K, acc);

    const int t = threadIdx.x, l = t & 63, lr = l & 15, lg = l >> 4;
    const int w = t >> 6, wm = (w >> 1) * 64, wc = w & 1;
#pragma unroll
    for (int mi = 0; mi < 4; mi++) {
        int row = m0 + wm + mi * 16 + lg * 4;
#pragma unroll
        for (int ni = 0; ni < 4; ni++) {
            int cb = wc * 32 + (ni & 1) * 16 + (ni >> 1) * 64;
            int col = n0 + cb + lr;
            float bv = bias[col];
#pragma unroll
            for (int j = 0; j < 4; j++)
                C[(size_t)(row + j) * N + col] = acc[mi][ni][j] + bv;
        }
    }
}

// ---------------- Flash attention (causal), KVB=64, single-buffered LDS ----
__global__ __launch_bounds__(256, 4)
void attn_fwd(const bfloat* __restrict__ Q, const bfloat* __restrict__ K,
              const bfloat* __restrict__ Vt, bfloat* __restrict__ O) {
    __shared__ bfloat Ks[64 * 128];
    __shared__ bfloat Vs[128 * 64];
    __shared__ bfloat Pw[4][16 * 64];

    const int t = threadIdx.x, w = t >> 6, l = t & 63;
    const int lr = l & 15, lg = l >> 4;
    const int swz = (lr & 7) << 4;

    const int f = blockIdx.x;
    const int xcd = f & 7, slot = f >> 3;
    const int bh = xcd + 8 * (slot >> 5);
    const int qidx = 31 - (slot & 31);
    const int b = bh >> 4, h = bh & 15;
    const int q0 = qidx * 64 + w * 16;

    const size_t bo_ = (size_t)b * SS * HH + (size_t)h * DHH;
    const bfloat* Qp = Q + bo_;
    const bfloat* Kp = K + bo_;
    const bfloat* Vp = Vt + (size_t)(b * NHH + h) * DHH * SS;
    bfloat* Op = O + bo_;

    auto stage = [&](int kv0) {
#pragma unroll
        for (int i = 0; i < 4; i++) {
            int Ub = (i * 4 + w) * 64;
            int U = Ub + l;
            int r = U >> 4;
            int u = (U & 15) ^ (r & 7);
            gload_lds16(Kp + (size_t)(kv0 + r) * HH + u * 8, &Ks[Ub * 8]);
        }
#pragma unroll
        for (int i = 0; i < 4; i++) {
            int Ub = (i * 4 + w) * 64;
            int U = Ub + l;
            int r = U >> 3;
            int u = (U & 7) ^ (r & 7);
            gload_lds16(Vp + (size_t)r * SS + kv0 + u * 8, &Vs[Ub * 8]);
        }
    };

    bf16x8 qf[4];
#pragma unroll
    for (int kt = 0; kt < 4; kt++)
        qf[kt] = *reinterpret_cast<const bf16x8*>(Qp + (size_t)(q0 + lr) * HH + kt * 32 + lg * 8);

    bf16x8 ones;
#pragma unroll
    for (int e = 0; e < 8; e++) ones[e] = (bfloat)1.0f;

    f32x4 o[8] = {};
    f32x4 lsv = {};
    float m[4];
#pragma unroll
    for (int j = 0; j < 4; j++) m[j] = -1e30f;

    const int nkv = qidx + 1;

    for (int kv = 0; kv < nkv; ++kv) {
        stage(kv * 64);
        __syncthreads();

        const char* KB = (const char*)&Ks[0];
        const char* VB = (const char*)&Vs[0];

        f32x4 sc[4] = {};
        __builtin_amdgcn_s_setprio(1);
#pragma unroll
        for (int kt = 0; kt < 4; kt++) {
            const int col = (kt * 64 + lg * 16);
#pragma unroll
            for (int kb = 0; kb < 4; kb++) {
                bf16x8 kf = *reinterpret_cast<const bf16x8*>(
                    KB + (kb * 16 + lr) * 256 + (col ^ swz));
                sc[kb] = mfma16(qf[kt], kf, sc[kb]);
            }
        }
        __builtin_amdgcn_s_setprio(0);

        const bool diag = (kv == nkv - 1);
        float p[4][4], alpha[4];
        bool ga = false;
#pragma unroll
        for (int j = 0; j < 4; j++) {
            float v0 = sc[0][j], v1 = sc[1][j], v2 = sc[2][j], v3 = sc[3][j];
            if (diag) {
                int qr = q0 + lg * 4 + j;
                int k0 = kv * 64 + lr;
                if (k0      > qr) v0 = -1e30f;
                if (k0 + 16 > qr) v1 = -1e30f;
                if (k0 + 32 > qr) v2 = -1e30f;
                if (k0 + 48 > qr) v3 = -1e30f;
            }
            float mx = rowmax16(fmaxf(fmaxf(v0, v1), fmaxf(v2, v3)));
            bool grow = mx > m[j] + 8.0f;
            float mn = grow ? mx : m[j];
            alpha[j] = grow ? __expf(m[j] - mn) : 1.0f;
            m[j] = mn;
            ga = ga || grow;
            p[0][j] = __expf(v0 - mn);
            p[1][j] = __expf(v1 - mn);
            p[2][j] = __expf(v2 - mn);
            p[3][j] = __expf(v3 - mn);
        }
        if (__any(ga)) {
#pragma unroll
            for (int j = 0; j < 4; j++) {
                lsv[j] *= alpha[j];
#pragma unroll
                for (int nt = 0; nt < 8; nt++) o[nt][j] *= alpha[j];
            }
        }

        char* pwb = (char*)&Pw[w][0];
#pragma unroll
        for (int j = 0; j < 4; j++) {
            int q = lg * 4 + j;
            int qs = (q & 7) << 4;
#pragma unroll
            for (int kb = 0; kb < 4; kb++)
                *(bfloat*)(pwb + q * 128 + ((kb * 32 + lr * 2) ^ qs)) = (bfloat)p[kb][j];
        }
        asm volatile("s_waitcnt lgkmcnt(0)" ::: "memory");
        __builtin_amdgcn_sched_barrier(0);

        const char* pwr = (const char*)&Pw[w][0];
        bf16x8 pa0 = *reinterpret_cast<const bf16x8*>(pwr + lr * 128 + ((lg * 16) ^ swz));
        bf16x8 pa1 = *reinterpret_cast<const bf16x8*>(pwr + lr * 128 + ((64 + lg * 16) ^ swz));
        __builtin_amdgcn_s_setprio(1);
        lsv = mfma16(pa0, ones, lsv);
        lsv = mfma16(pa1, ones, lsv);
#pragma unroll
        for (int nt = 0; nt < 8; nt++) {
            const char* vb = VB + (nt * 16 + lr) * 128;
            bf16x8 vf0 = *reinterpret_cast<const bf16x8*>(vb + ((lg * 16) ^ swz));
            bf16x8 vf1 = *reinterpret_cast<const bf16x8*>(vb + ((64 + lg * 16) ^ swz));
            o[nt] = mfma16(pa0, vf0, o[nt]);
            o[nt] = mfma16(pa1, vf1, o[nt]);
        }
        __builtin_amdgcn_s_setprio(0);
        __syncthreads();
    }

#pragma unroll
    for (int j = 0; j < 4; j++) {
        float inv = 1.0f / lsv[j];
        int row = q0 + lg * 4 + j;
#pragma unroll
        for (int nt = 0; nt < 8; nt++)
            Op[(size_t)row * HH + nt * 16 + lr] = (bfloat)(o[nt][j] * inv);
    }
}

// ---------------- launch ----------------
extern "C" void kernel_launch(void* const* d_in, const int* in_sizes, int n_in,
                              void* d_out, int out_size, void* d_ws, size_t ws_size,
                              hipStream_t stream) {
    (void)in_sizes; (void)n_in; (void)out_size; (void)ws_size;
    const float* hs = (const float*)d_in[0];
    const float* Wq = (const float*)d_in[2];
    const float* bq = (const float*)d_in[3];
    const float* Wk = (const float*)d_in[4];
    const float* bk = (const float*)d_in[5];
    const float* Wv = (const float*)d_in[6];
    const float* bv = (const float*)d_in[7];
    const float* Wo = (const float*)d_in[8];
    const float* bo = (const float*)d_in[9];

    char* ws = (char*)d_ws;
    size_t off = 0;
    auto alloc = [&](size_t bytes) { void* p = ws + off; off += (bytes + 255) & ~(size_t)255; return p; };
    const size_t MK = (size_t)BB * SS * HH;   // 8M elems
    const size_t NK = (size_t)HH * HH;        // 4M elems

    bfloat* Xb  = (bfloat*)alloc(MK * 2);
    bfloat* Wqb = (bfloat*)alloc(NK * 2);
    bfloat* Wkb = (bfloat*)alloc(NK * 2);
    bfloat* Wvb = (bfloat*)alloc(NK * 2);
    bfloat* Wob = (bfloat*)alloc(NK * 2);
    bfloat* Qb  = (bfloat*)alloc(MK * 2);
    bfloat* Kb  = (bfloat*)alloc(MK * 2);
    bfloat* Vtb = (bfloat*)alloc(MK * 2);     // (b, h, d, s)
    float*  cosT = (float*)alloc((size_t)SS * 64 * 4);
    float*  sinT = (float*)alloc((size_t)SS * 64 * 4);
    bfloat* AOb = Xb;   // reuse: X no longer needed after QKV GEMM

    prep_all<<<8192 + 16384 + 512, 256, 0, stream>>>(
        hs, Wq, Wk, Wv, Wo, Xb, Wqb, Wkb, Wvb, Wob, cosT, sinT);

    gemm_qkv<<<dim3(32, 48), 256, 0, stream>>>(
        Xb, Wqb, Wkb, Wvb, bq, bk, bv, Qb, Kb, Vtb, cosT, sinT);

    attn_fwd<<<1024, 256, 0, stream>>>(Qb, Kb, Vtb, AOb);

    gemm_out<<<dim3(32, 16), 256, 0, stream>>>(AOb, Wob, bo, (float*)d_out);
}

// Round 14
// 272.386 us; speedup vs baseline: 1.2063x; 1.1295x over previous
//
#include <hip/hip_runtime.h>
#include <hip/hip_bf16.h>
#include <cstdint>
#include <cstddef>

#define BB 2
#define SS 2048
#define HH 2048
#define NHH 16
#define DHH 128

using f32x4  = __attribute__((ext_vector_type(4))) float;
using bf16x8 = __attribute__((ext_vector_type(8))) __bf16;
using bf16x4 = __attribute__((ext_vector_type(4))) __bf16;
using bfloat = __bf16;

__device__ inline void gload_lds16(const void* g, void* l) {
    __builtin_amdgcn_global_load_lds(
        (const __attribute__((address_space(1))) void*)g,
        (__attribute__((address_space(3))) void*)l, 16, 0, 0);
}

__device__ inline f32x4 mfma16(bf16x8 a, bf16x8 b, f32x4 c) {
    return __builtin_amdgcn_mfma_f32_16x16x32_bf16(a, b, c, 0, 0, 0);
}

template <int CTRL>
__device__ inline float dpp_max_step(float x) {
    int y = __builtin_amdgcn_update_dpp(0, __builtin_bit_cast(int, x), CTRL, 0xf, 0xf, false);
    return fmaxf(x, __builtin_bit_cast(float, y));
}
__device__ inline float rowmax16(float x) {
    x = dpp_max_step<0x121>(x);
    x = dpp_max_step<0x122>(x);
    x = dpp_max_step<0x124>(x);
    x = dpp_max_step<0x128>(x);
    return x;
}

// -------- merged prep: X cvt (8192 blk) + 4 weight cvts (16384 blk) + rope (512 blk)
__global__ void prep_all(const float* __restrict__ hs,
                         const float* __restrict__ w0, const float* __restrict__ w1,
                         const float* __restrict__ w2, const float* __restrict__ w3,
                         bfloat* __restrict__ xb,
                         bfloat* __restrict__ d0, bfloat* __restrict__ d1,
                         bfloat* __restrict__ d2, bfloat* __restrict__ d3,
                         float* __restrict__ cosT, float* __restrict__ sinT) {
    const int bid = blockIdx.x, tid = threadIdx.x;
    if (bid < 8192 + 16384) {
        const float* s;
        bfloat* d;
        int i;
        if (bid < 8192) {
            s = hs; d = xb; i = bid * 256 + tid;
        } else {
            int b2 = bid - 8192, sel = b2 >> 12;
            s = sel == 0 ? w0 : sel == 1 ? w1 : sel == 2 ? w2 : w3;
            d = sel == 0 ? d0 : sel == 1 ? d1 : sel == 2 ? d2 : d3;
            i = (b2 & 4095) * 256 + tid;
        }
        float4 v = reinterpret_cast<const float4*>(s)[i];
        bf16x4 o;
        o[0] = (bfloat)v.x; o[1] = (bfloat)v.y; o[2] = (bfloat)v.z; o[3] = (bfloat)v.w;
        reinterpret_cast<bf16x4*>(d)[i] = o;
    } else {
        int i = (bid - 24576) * 256 + tid;      // 0 .. SS*64-1
        int s = i >> 6, j = i & 63;
        float invf = powf(10000.0f, -(float)j / 64.0f);
        float ang = (float)s * invf;
        cosT[i] = cosf(ang);
        sinT[i] = sinf(ang);
    }
}

// ======== 128x128 tile K-loop, BK=32, 4 waves, ONE barrier per K-tile ==========
// (R13 verbatim -- best measured GEMM core.)
__device__ __forceinline__ void kloop128(const bfloat* __restrict__ Ag,
                                         const bfloat* __restrict__ Bg,
                                         f32x4 (&acc)[4][4]) {
    constexpr int K = HH, NT = K / 32;
    __shared__ bfloat As[2][128 * 32];
    __shared__ bfloat Bs[2][128 * 32];
    const int t = threadIdx.x, l = t & 63, lr = l & 15, lg = l >> 4;
    const int w = t >> 6, wm = (w >> 1) * 64, wc = w & 1;
    const int ubase = t & ~63;

    auto stage = [&](int buf, int kt) {
#pragma unroll
        for (int i = 0; i < 2; i++) {
            int idx = i * 256 + t;
            int r = idx >> 2, u = idx & 3;
            int us = u ^ (r & 3) ^ ((r >> 2) & 1);
            gload_lds16(Ag + (size_t)r * K + kt * 32 + us * 8,
                        &As[buf][(i * 256 + ubase) * 8]);
        }
#pragma unroll
        for (int i = 0; i < 2; i++) {
            int idx = i * 256 + t;
            int r = idx >> 2, u = idx & 3;
            int us = u ^ (r & 3) ^ ((r >> 2) & 1);
            gload_lds16(Bg + (size_t)r * K + kt * 32 + us * 8,
                        &Bs[buf][(i * 256 + ubase) * 8]);
        }
    };

    stage(0, 0);

#pragma unroll 1
    for (int kt = 0; kt < NT; ++kt) {
        const int buf = kt & 1;
        asm volatile("s_waitcnt vmcnt(0)" ::: "memory");
        __builtin_amdgcn_s_barrier();
        __builtin_amdgcn_sched_barrier(0);
        if (kt + 1 < NT) stage(buf ^ 1, kt + 1);

        const bfloat* A_ = As[buf];
        const bfloat* B_ = Bs[buf];
        bf16x8 af[4], bfr[4];
#pragma unroll
        for (int mi = 0; mi < 4; mi++) {
            int row = wm + mi * 16 + lr;
            int us = lg ^ (row & 3) ^ ((row >> 2) & 1);
            af[mi] = *reinterpret_cast<const bf16x8*>(&A_[row * 32 + us * 8]);
        }
#pragma unroll
        for (int ni = 0; ni < 4; ni++) {
            int row = wc * 32 + (ni & 1) * 16 + (ni >> 1) * 64 + lr;
            int us = lg ^ (row & 3) ^ ((row >> 2) & 1);
            bfr[ni] = *reinterpret_cast<const bf16x8*>(&B_[row * 32 + us * 8]);
        }
        __builtin_amdgcn_s_setprio(1);
#pragma unroll
        for (int mi = 0; mi < 4; mi++)
#pragma unroll
            for (int ni = 0; ni < 4; ni++)
                acc[mi][ni] = mfma16(af[mi], bfr[ni], acc[mi][ni]);
        __builtin_amdgcn_s_setprio(0);
        __builtin_amdgcn_sched_barrier(0);
    }
}

// ================= fused QKV GEMM (128x128 tiles, 256 threads) =================
__global__ __launch_bounds__(256, 4)
void gemm_qkv(const bfloat* __restrict__ A,
              const bfloat* __restrict__ Bq, const bfloat* __restrict__ Bk,
              const bfloat* __restrict__ Bv,
              const float* __restrict__ bq, const float* __restrict__ bk,
              const float* __restrict__ bv,
              bfloat* __restrict__ Qo, bfloat* __restrict__ Ko, bfloat* __restrict__ Vto,
              const float* __restrict__ cosT, const float* __restrict__ sinT) {
    constexpr int K = HH, N = HH;
    const int sel = blockIdx.y >> 4;
    const bfloat* Bt = sel == 0 ? Bq : sel == 1 ? Bk : Bv;
    const float* bias = sel == 0 ? bq : sel == 1 ? bk : bv;
    const int m0 = blockIdx.x * 128, n0 = (blockIdx.y & 15) * 128;

    f32x4 acc[4][4] = {};
    kloop128(A + (size_t)m0 * K, Bt + (size_t)n0 * K, acc);

    const int t = threadIdx.x, l = t & 63, lr = l & 15, lg = l >> 4;
    const int w = t >> 6, wm = (w >> 1) * 64, wc = w & 1;

    if (sel == 2) {   // V: write transposed (b, h, d, s) -- j-packed stores
#pragma unroll
        for (int mi = 0; mi < 4; mi++) {
            int row = m0 + wm + mi * 16 + lg * 4;
            int bb = row >> 11;
            int s0 = row & (SS - 1);
#pragma unroll
            for (int ni = 0; ni < 4; ni++) {
                int cb = wc * 32 + (ni & 1) * 16 + (ni >> 1) * 64;
                int col = n0 + cb + lr;
                float bv_ = bias[col];
                bf16x4 pack;
#pragma unroll
                for (int j = 0; j < 4; j++)
                    pack[j] = (bfloat)(acc[mi][ni][j] + bv_);
                *reinterpret_cast<bf16x4*>(
                    &Vto[((size_t)(bb * HH + col)) * SS + s0]) = pack;
            }
        }
    } else {          // Q/K: RoPE epilogue (Q also pre-scaled by 1/sqrt(DH))
        bfloat* C = sel == 0 ? Qo : Ko;
        const float qs = sel == 0 ? 0.088388347648318447f : 1.0f;
#pragma unroll
        for (int mi = 0; mi < 4; mi++) {
            int row = m0 + wm + mi * 16 + lg * 4;
#pragma unroll
            for (int ni = 0; ni < 2; ni++) {
                int d = wc * 32 + ni * 16 + lr;
                int col1 = n0 + d, col2 = col1 + 64;
                float b1 = bias[col1], b2 = bias[col2];
#pragma unroll
                for (int j = 0; j < 4; j++) {
                    int r = row + j, s = r & (SS - 1);
                    float c  = cosT[s * 64 + d];
                    float sn = sinT[s * 64 + d];
                    float x1 = acc[mi][ni][j] + b1;
                    float x2 = acc[mi][ni + 2][j] + b2;
                    C[(size_t)r * N + col1] = (bfloat)((x1 * c - x2 * sn) * qs);
                    C[(size_t)r * N + col2] = (bfloat)((x2 * c + x1 * sn) * qs);
                }
            }
        }
    }
}

// ---------------- out-proj GEMM (128x128 tiles, f32 out) ----------------
__global__ __launch_bounds__(256, 4)
void gemm_out(const bfloat* __restrict__ A, const bfloat* __restrict__ Bt,
              const float* __restrict__ bias, float* __restrict__ C) {
    constexpr int K = HH, N = HH;
    const int m0 = blockIdx.x * 128, n0 = blockIdx.y * 128;

    f32x4 acc[4][4] = {};
    kloop128(A + (size_t)m0 * K, Bt + (size_t)n0 * K, acc);

    const int t = threadIdx.x, l = t & 63, lr = l & 15, lg = l >> 4;
    const int w = t >> 6, wm = (w >> 1) * 64, wc = w & 1;
#pragma unroll
    for (int mi = 0; mi < 4; mi++) {
        int row = m0 + wm + mi * 16 + lg * 4;
#pragma unroll
        for (int ni = 0; ni < 4; ni++) {
            int cb = wc * 32 + (ni & 1) * 16 + (ni >> 1) * 64;
            int col = n0 + cb + lr;
            float bv = bias[col];
#pragma unroll
            for (int j = 0; j < 4; j++)
                C[(size_t)(row + j) * N + col] = acc[mi][ni][j] + bv;
        }
    }
}

// ---------------- Flash attention (causal), PAIRED q-tiles, dbuf K/V ----------
// Block p handles q-tiles {p, 31-p}: every block = exactly 33 tile-computes,
// one shared KV sweep kv=0..31-p (tile A active while kv<=p).  Grid 512 =
// 2 blocks/CU, all resident, perfectly balanced regardless of dispatch order.
// K/V double-buffered; single barrier per kv (GEMM-style): vmcnt(0) -> barrier
// -> stage(kv+1 -> buf^1) overlapping compute(buf).
__global__ __launch_bounds__(256, 2)
void attn_fwd(const bfloat* __restrict__ Q, const bfloat* __restrict__ K,
              const bfloat* __restrict__ Vt, bfloat* __restrict__ O) {
    __shared__ bfloat Ks[2][64 * 128];
    __shared__ bfloat Vs[2][128 * 64];
    __shared__ bfloat Pw[4][16 * 64];

    const int t = threadIdx.x, w = t >> 6, l = t & 63;
    const int lr = l & 15, lg = l >> 4;
    const int swz = (lr & 7) << 4;

    const int f = blockIdx.x;            // 0..511
    const int bh = f & 31, p = f >> 5;   // head, pair index 0..15
    const int qa = p, qb = 31 - p;
    const int b = bh >> 4, h = bh & 15;
    const int q0a = qa * 64 + w * 16, q0b = qb * 64 + w * 16;

    const size_t bo_ = (size_t)b * SS * HH + (size_t)h * DHH;
    const bfloat* Qp = Q + bo_;
    const bfloat* Kp = K + bo_;
    const bfloat* Vp = Vt + (size_t)(b * NHH + h) * DHH * SS;
    bfloat* Op = O + bo_;

    auto stage = [&](int buf, int kv0) {
#pragma unroll
        for (int i = 0; i < 4; i++) {
            int Ub = (i * 4 + w) * 64;
            int U = Ub + l;
            int r = U >> 4;
            int u = (U & 15) ^ (r & 7);
            gload_lds16(Kp + (size_t)(kv0 + r) * HH + u * 8, &Ks[buf][Ub * 8]);
        }
#pragma unroll
        for (int i = 0; i < 4; i++) {
            int Ub = (i * 4 + w) * 64;
            int U = Ub + l;
            int r = U >> 3;
            int u = (U & 7) ^ (r & 7);
            gload_lds16(Vp + (size_t)r * SS + kv0 + u * 8, &Vs[buf][Ub * 8]);
        }
    };

    bf16x8 qfA[4], qfB[4];
#pragma unroll
    for (int kt = 0; kt < 4; kt++) {
        qfA[kt] = *reinterpret_cast<const bf16x8*>(Qp + (size_t)(q0a + lr) * HH + kt * 32 + lg * 8);
        qfB[kt] = *reinterpret_cast<const bf16x8*>(Qp + (size_t)(q0b + lr) * HH + kt * 32 + lg * 8);
    }

    bf16x8 ones;
#pragma unroll
    for (int e = 0; e < 8; e++) ones[e] = (bfloat)1.0f;

    f32x4 oA[8] = {}, oB[8] = {};
    f32x4 lsvA = {}, lsvB = {};
    float mA[4], mB[4];
#pragma unroll
    for (int j = 0; j < 4; j++) { mA[j] = -1e30f; mB[j] = -1e30f; }

    // one tile-compute: QK^T -> masked softmax (defer-max) -> P -> PV (+rowsum)
    auto process = [&](bf16x8 (&qf)[4], f32x4 (&o)[8], f32x4& lsv, float (&m)[4],
                       int q0, int kv, bool diag, const char* KB, const char* VB) {
        f32x4 sc[4] = {};
        __builtin_amdgcn_s_setprio(1);
#pragma unroll
        for (int kt = 0; kt < 4; kt++) {
            const int col = (kt * 64 + lg * 16);
#pragma unroll
            for (int kb = 0; kb < 4; kb++) {
                bf16x8 kf = *reinterpret_cast<const bf16x8*>(
                    KB + (kb * 16 + lr) * 256 + (col ^ swz));
                sc[kb] = mfma16(qf[kt], kf, sc[kb]);
            }
        }
        __builtin_amdgcn_s_setprio(0);

        float pv[4][4], alpha[4];
        bool ga = false;
#pragma unroll
        for (int j = 0; j < 4; j++) {
            float v0 = sc[0][j], v1 = sc[1][j], v2 = sc[2][j], v3 = sc[3][j];
            if (diag) {
                int qr = q0 + lg * 4 + j;
                int k0 = kv * 64 + lr;
                if (k0      > qr) v0 = -1e30f;
                if (k0 + 16 > qr) v1 = -1e30f;
                if (k0 + 32 > qr) v2 = -1e30f;
                if (k0 + 48 > qr) v3 = -1e30f;
            }
            float mx = rowmax16(fmaxf(fmaxf(v0, v1), fmaxf(v2, v3)));
            bool grow = mx > m[j] + 8.0f;
            float mn = grow ? mx : m[j];
            alpha[j] = grow ? __expf(m[j] - mn) : 1.0f;
            m[j] = mn;
            ga = ga || grow;
            pv[0][j] = __expf(v0 - mn);
            pv[1][j] = __expf(v1 - mn);
            pv[2][j] = __expf(v2 - mn);
            pv[3][j] = __expf(v3 - mn);
        }
        if (__any(ga)) {
#pragma unroll
            for (int j = 0; j < 4; j++) {
                lsv[j] *= alpha[j];
#pragma unroll
                for (int nt = 0; nt < 8; nt++) o[nt][j] *= alpha[j];
            }
        }

        char* pwb = (char*)&Pw[w][0];
#pragma unroll
        for (int j = 0; j < 4; j++) {
            int q = lg * 4 + j;
            int qs = (q & 7) << 4;
#pragma unroll
            for (int kb = 0; kb < 4; kb++)
                *(bfloat*)(pwb + q * 128 + ((kb * 32 + lr * 2) ^ qs)) = (bfloat)pv[kb][j];
        }
        asm volatile("s_waitcnt lgkmcnt(0)" ::: "memory");
        __builtin_amdgcn_sched_barrier(0);

        const char* pwr = (const char*)&Pw[w][0];
        bf16x8 pa0 = *reinterpret_cast<const bf16x8*>(pwr + lr * 128 + ((lg * 16) ^ swz));
        bf16x8 pa1 = *reinterpret_cast<const bf16x8*>(pwr + lr * 128 + ((64 + lg * 16) ^ swz));
        __builtin_amdgcn_s_setprio(1);
        lsv = mfma16(pa0, ones, lsv);
        lsv = mfma16(pa1, ones, lsv);
#pragma unroll
        for (int nt = 0; nt < 8; nt++) {
            const char* vb = VB + (nt * 16 + lr) * 128;
            bf16x8 vf0 = *reinterpret_cast<const bf16x8*>(vb + ((lg * 16) ^ swz));
            bf16x8 vf1 = *reinterpret_cast<const bf16x8*>(vb + ((64 + lg * 16) ^ swz));
            o[nt] = mfma16(pa0, vf0, o[nt]);
            o[nt] = mfma16(pa1, vf1, o[nt]);
        }
        __builtin_amdgcn_s_setprio(0);
    };

    const int nkv = qb + 1;
    stage(0, 0);

#pragma unroll 1
    for (int kv = 0; kv < nkv; ++kv) {
        const int buf = kv & 1;
        asm volatile("s_waitcnt vmcnt(0)" ::: "memory");   // own stage(kv) landed
        __builtin_amdgcn_s_barrier();                      // all landed; prev reads done
        __builtin_amdgcn_sched_barrier(0);
        if (kv + 1 < nkv) stage(buf ^ 1, (kv + 1) * 64);   // overlaps compute

        const char* KB = (const char*)&Ks[buf][0];
        const char* VB = (const char*)&Vs[buf][0];

        process(qfB, oB, lsvB, mB, q0b, kv, kv == qb, KB, VB);
        if (kv <= qa)
            process(qfA, oA, lsvA, mA, q0a, kv, kv == qa, KB, VB);
    }

    auto epi = [&](f32x4 (&o)[8], f32x4& lsv, int q0) {
#pragma unroll
        for (int j = 0; j < 4; j++) {
            float inv = 1.0f / lsv[j];
            int row = q0 + lg * 4 + j;
#pragma unroll
            for (int nt = 0; nt < 8; nt++)
                Op[(size_t)row * HH + nt * 16 + lr] = (bfloat)(o[nt][j] * inv);
        }
    };
    epi(oB, lsvB, q0b);
    epi(oA, lsvA, q0a);
}

// ---------------- launch ----------------
extern "C" void kernel_launch(void* const* d_in, const int* in_sizes, int n_in,
                              void* d_out, int out_size, void* d_ws, size_t ws_size,
                              hipStream_t stream) {
    (void)in_sizes; (void)n_in; (void)out_size; (void)ws_size;
    const float* hs = (const float*)d_in[0];
    const float* Wq = (const float*)d_in[2];
    const float* bq = (const float*)d_in[3];
    const float* Wk = (const float*)d_in[4];
    const float* bk = (const float*)d_in[5];
    const float* Wv = (const float*)d_in[6];
    const float* bv = (const float*)d_in[7];
    const float* Wo = (const float*)d_in[8];
    const float* bo = (const float*)d_in[9];

    char* ws = (char*)d_ws;
    size_t off = 0;
    auto alloc = [&](size_t bytes) { void* p = ws + off; off += (bytes + 255) & ~(size_t)255; return p; };
    const size_t MK = (size_t)BB * SS * HH;   // 8M elems
    const size_t NK = (size_t)HH * HH;        // 4M elems

    bfloat* Xb  = (bfloat*)alloc(MK * 2);
    bfloat* Wqb = (bfloat*)alloc(NK * 2);
    bfloat* Wkb = (bfloat*)alloc(NK * 2);
    bfloat* Wvb = (bfloat*)alloc(NK * 2);
    bfloat* Wob = (bfloat*)alloc(NK * 2);
    bfloat* Qb  = (bfloat*)alloc(MK * 2);
    bfloat* Kb  = (bfloat*)alloc(MK * 2);
    bfloat* Vtb = (bfloat*)alloc(MK * 2);     // (b, h, d, s)
    float*  cosT = (float*)alloc((size_t)SS * 64 * 4);
    float*  sinT = (float*)alloc((size_t)SS * 64 * 4);
    bfloat* AOb = Xb;   // reuse: X no longer needed after QKV GEMM

    prep_all<<<8192 + 16384 + 512, 256, 0, stream>>>(
        hs, Wq, Wk, Wv, Wo, Xb, Wqb, Wkb, Wvb, Wob, cosT, sinT);

    gemm_qkv<<<dim3(32, 48), 256, 0, stream>>>(
        Xb, Wqb, Wkb, Wvb, bq, bk, bv, Qb, Kb, Vtb, cosT, sinT);

    attn_fwd<<<512, 256, 0, stream>>>(Qb, Kb, Vtb, AOb);

    gemm_out<<<dim3(32, 16), 256, 0, stream>>>(AOb, Wob, bo, (float*)d_out);
}